// Round 1
// baseline (1813.171 us; speedup 1.0000x reference)
//
#include <hip/hip_runtime.h>
#include <math.h>

#define N_ROWS 32768
#define DIM    256
#define KC     1024
#define BM     64
#define BN     64
#define DSTEP  32
#define PAD_M  68          // LDS row stride in floats: 68*4=272 B, 16B-aligned
#define EPS_MARGIN 1e-4f

// ---------------- codebook squared norms ----------------
__global__ __launch_bounds__(256) void enorm_kernel(const float* __restrict__ emb,
                                                    float* __restrict__ enorm) {
    int k = blockIdx.x * blockDim.x + threadIdx.x;
    if (k >= KC) return;
    const float4* row = (const float4*)(emb + (size_t)k * DIM);
    float s = 0.f;
    #pragma unroll 4
    for (int i = 0; i < DIM / 4; ++i) {
        float4 v = row[i];
        s += v.x * v.x + v.y * v.y + v.z * v.z + v.w * v.w;
    }
    enorm[k] = s;
}

// ---------------- phase 1: fp32 distances + best2 argmin ----------------
__global__ __launch_bounds__(256) void argmin_kernel(const float* __restrict__ lat,
                                                     const float* __restrict__ emb,
                                                     const float* __restrict__ enorm,
                                                     int* __restrict__ inds,
                                                     float* __restrict__ margin) {
    __shared__ float As[DSTEP][PAD_M];   // As[d][m]
    __shared__ float Bs[DSTEP][PAD_M];   // Bs[d][n]
    __shared__ float rbest[BM][17];
    __shared__ float rsec[BM][17];
    __shared__ int   ridx[BM][17];

    const int tid = threadIdx.x;
    const int tx = tid & 15;          // column group
    const int ty = tid >> 4;          // row group
    const int row0 = blockIdx.x * BM;

    const int lm  = tid >> 2;         // 0..63: which row/col this thread stages
    const int ld0 = (tid & 3) * 8;    // d offset for staging (8 floats)

    float best[4], sec[4];
    int bidx[4];
    #pragma unroll
    for (int i = 0; i < 4; ++i) { best[i] = INFINITY; sec[i] = INFINITY; bidx[i] = 0; }

    for (int ct = 0; ct < KC / BN; ++ct) {
        float acc[4][4];
        #pragma unroll
        for (int i = 0; i < 4; ++i)
            #pragma unroll
            for (int j = 0; j < 4; ++j) acc[i][j] = 0.f;

        for (int dc = 0; dc < DIM; dc += DSTEP) {
            // stage A tile (64 rows x 32 d), transposed to d-major
            const float* ap = lat + (size_t)(row0 + lm) * DIM + dc + ld0;
            float4 a0 = *(const float4*)ap;
            float4 a1 = *(const float4*)(ap + 4);
            As[ld0 + 0][lm] = a0.x; As[ld0 + 1][lm] = a0.y;
            As[ld0 + 2][lm] = a0.z; As[ld0 + 3][lm] = a0.w;
            As[ld0 + 4][lm] = a1.x; As[ld0 + 5][lm] = a1.y;
            As[ld0 + 6][lm] = a1.z; As[ld0 + 7][lm] = a1.w;
            // stage B tile (64 cols x 32 d), transposed to d-major
            const float* bp = emb + (size_t)(ct * BN + lm) * DIM + dc + ld0;
            float4 b0 = *(const float4*)bp;
            float4 b1 = *(const float4*)(bp + 4);
            Bs[ld0 + 0][lm] = b0.x; Bs[ld0 + 1][lm] = b0.y;
            Bs[ld0 + 2][lm] = b0.z; Bs[ld0 + 3][lm] = b0.w;
            Bs[ld0 + 4][lm] = b1.x; Bs[ld0 + 5][lm] = b1.y;
            Bs[ld0 + 6][lm] = b1.z; Bs[ld0 + 7][lm] = b1.w;
            __syncthreads();

            #pragma unroll
            for (int d = 0; d < DSTEP; ++d) {
                float4 av = *(const float4*)&As[d][ty * 4];
                float4 bv = *(const float4*)&Bs[d][tx * 4];
                float a[4] = {av.x, av.y, av.z, av.w};
                float b[4] = {bv.x, bv.y, bv.z, bv.w};
                #pragma unroll
                for (int i = 0; i < 4; ++i)
                    #pragma unroll
                    for (int j = 0; j < 4; ++j)
                        acc[i][j] = fmaf(a[i], b[j], acc[i][j]);
            }
            __syncthreads();
        }

        // epilogue for this column tile: dist = enorm[n] - 2*dot
        #pragma unroll
        for (int j = 0; j < 4; ++j) {
            int n = ct * BN + tx * 4 + j;
            float en = enorm[n];
            #pragma unroll
            for (int i = 0; i < 4; ++i) {
                float dist = fmaf(-2.f, acc[i][j], en);
                if (dist < best[i]) { sec[i] = best[i]; best[i] = dist; bidx[i] = n; }
                else if (dist < sec[i]) sec[i] = dist;
            }
        }
    }

    // cross-thread (over tx) reduction per row
    #pragma unroll
    for (int i = 0; i < 4; ++i) {
        rbest[ty * 4 + i][tx] = best[i];
        rsec [ty * 4 + i][tx] = sec[i];
        ridx [ty * 4 + i][tx] = bidx[i];
    }
    __syncthreads();
    if (tid < BM) {
        float g1 = INFINITY, g2 = INFINITY;
        int i1 = 0x7fffffff;
        for (int t = 0; t < 16; ++t) {
            float d = rbest[tid][t];
            float s = rsec[tid][t];
            int   ix = ridx[tid][t];
            if (d < g1 || (d == g1 && ix < i1)) {
                g2 = fminf(g2, g1);
                g1 = d; i1 = ix;
                g2 = fminf(g2, s);
            } else {
                g2 = fminf(g2, d);
            }
        }
        inds[row0 + tid] = i1;
        margin[row0 + tid] = g2 - g1;
    }
}

// ---------------- phase 2: f64 refine for near-tie rows ----------------
__global__ __launch_bounds__(256) void refine_kernel(const float* __restrict__ lat,
                                                     const float* __restrict__ emb,
                                                     const float* __restrict__ margin,
                                                     int* __restrict__ inds) {
    const int lane = threadIdx.x & 63;
    const int w = threadIdx.x >> 6;
    const int gw = blockIdx.x * 4 + w;        // 2048 waves, 16 rows each
    for (int r = 0; r < 16; ++r) {
        int row = gw * 16 + r;
        if (margin[row] > EPS_MARGIN) continue;   // wave-uniform branch
        const float* xp = lat + (size_t)row * DIM + lane * 4;
        double t0 = 2.0 * (double)xp[0];
        double t1 = 2.0 * (double)xp[1];
        double t2 = 2.0 * (double)xp[2];
        double t3 = 2.0 * (double)xp[3];
        double bestd = INFINITY;
        int besti = 0;
        for (int k = 0; k < KC; ++k) {
            const float* ep = emb + (size_t)k * DIM + lane * 4;
            double e0 = ep[0], e1 = ep[1], e2 = ep[2], e3 = ep[3];
            double p = e0 * (e0 - t0) + e1 * (e1 - t1)
                     + e2 * (e2 - t2) + e3 * (e3 - t3);   // e^2 - 2xe partial
            #pragma unroll
            for (int off = 32; off >= 1; off >>= 1) p += __shfl_xor(p, off);
            if (p < bestd) { bestd = p; besti = k; }      // strict <: first index wins
        }
        if (lane == 0) inds[row] = besti;
    }
}

// ---------------- histogram of codes ----------------
__global__ __launch_bounds__(256) void hist_kernel(const int* __restrict__ inds,
                                                   int* __restrict__ hist) {
    int r = blockIdx.x * 256 + threadIdx.x;
    if (r < N_ROWS) atomicAdd(&hist[inds[r]], 1);
}

// ---------------- gather + quantized_st + MSE partials ----------------
__global__ __launch_bounds__(256) void gather_kernel(const float* __restrict__ lat,
                                                     const float* __restrict__ emb,
                                                     const int* __restrict__ inds,
                                                     float* __restrict__ out,
                                                     double* __restrict__ partials) {
    __shared__ double wsum[4];
    const int tid = threadIdx.x;
    double acc = 0.0;
    const int nvec = N_ROWS * DIM / 4;   // float4 count
    for (int idx = blockIdx.x * blockDim.x + tid; idx < nvec; idx += gridDim.x * blockDim.x) {
        int row = idx >> 6;              // 64 float4 per row
        int dv = idx & 63;
        int k = inds[row];
        float4 xv = ((const float4*)lat)[idx];
        float4 qv = ((const float4*)(emb + (size_t)k * DIM))[dv];
        float d0 = qv.x - xv.x, d1 = qv.y - xv.y, d2 = qv.z - xv.z, d3 = qv.w - xv.w;
        float4 o;
        o.x = xv.x + d0; o.y = xv.y + d1; o.z = xv.z + d2; o.w = xv.w + d3;
        ((float4*)out)[idx] = o;
        acc += (double)d0 * d0 + (double)d1 * d1 + (double)d2 * d2 + (double)d3 * d3;
    }
    #pragma unroll
    for (int off = 32; off >= 1; off >>= 1) acc += __shfl_xor(acc, off);
    if ((tid & 63) == 0) wsum[tid >> 6] = acc;
    __syncthreads();
    if (tid == 0) partials[blockIdx.x] = wsum[0] + wsum[1] + wsum[2] + wsum[3];
}

// ---------------- finalize: vq_loss + perplexity ----------------
__global__ __launch_bounds__(256) void finalize_kernel(const int* __restrict__ hist,
                                                       const double* __restrict__ partials,
                                                       float* __restrict__ out_tail) {
    __shared__ double sh[256];
    const int tid = threadIdx.x;
    double s = 0.0;
    for (int i = tid; i < 2048; i += 256) s += partials[i];
    sh[tid] = s; __syncthreads();
    for (int st = 128; st > 0; st >>= 1) {
        if (tid < st) sh[tid] += sh[tid + st];
        __syncthreads();
    }
    double sumsq = sh[0];
    __syncthreads();

    double e = 0.0;
    for (int k = tid; k < KC; k += 256) {
        double p = (double)hist[k] / (double)N_ROWS;
        e += p * log(p + 1e-10);
    }
    sh[tid] = e; __syncthreads();
    for (int st = 128; st > 0; st >>= 1) {
        if (tid < st) sh[tid] += sh[tid + st];
        __syncthreads();
    }
    if (tid == 0) {
        double mse = sumsq / (double)((size_t)N_ROWS * DIM);
        out_tail[0] = (float)(1.25 * mse);      // beta*commitment + embedding = 1.25*mse
        out_tail[1] = (float)exp(-sh[0]);       // perplexity
    }
}

extern "C" void kernel_launch(void* const* d_in, const int* in_sizes, int n_in,
                              void* d_out, int out_size, void* d_ws, size_t ws_size,
                              hipStream_t stream) {
    const float* lat = (const float*)d_in[0];
    const float* emb = (const float*)d_in[1];
    float* out = (float*)d_out;

    char* ws = (char*)d_ws;
    int*    hist     = (int*)(ws);                       // 4 KB
    float*  enorm    = (float*)(ws + 4096);              // 4 KB
    int*    inds     = (int*)(ws + 8192);                // 128 KB
    float*  margin   = (float*)(ws + 8192 + 131072);     // 128 KB
    double* partials = (double*)(ws + 8192 + 262144);    // 16 KB

    hipMemsetAsync(hist, 0, KC * sizeof(int), stream);
    enorm_kernel<<<KC / 256, 256, 0, stream>>>(emb, enorm);
    argmin_kernel<<<N_ROWS / BM, 256, 0, stream>>>(lat, emb, enorm, inds, margin);
    refine_kernel<<<512, 256, 0, stream>>>(lat, emb, margin, inds);
    hist_kernel<<<N_ROWS / 256, 256, 0, stream>>>(inds, hist);
    gather_kernel<<<2048, 256, 0, stream>>>(lat, emb, inds, out, partials);
    finalize_kernel<<<1, 256, 0, stream>>>(hist, partials, out + (size_t)N_ROWS * DIM);
}

// Round 2
// 495.961 us; speedup vs baseline: 3.6559x; 3.6559x over previous
//
#include <hip/hip_runtime.h>
#include <math.h>

#define N_ROWS 32768
#define DIM    256
#define KC     1024
#define BM     64
#define BN     64
#define DSTEP  32
#define PAD_M  68          // LDS row stride in floats: 68*4=272 B, 16B-aligned
#define EPS_MARGIN 1e-4f

// ---------------- codebook squared norms ----------------
__global__ __launch_bounds__(256) void enorm_kernel(const float* __restrict__ emb,
                                                    float* __restrict__ enorm) {
    int k = blockIdx.x * blockDim.x + threadIdx.x;
    if (k >= KC) return;
    const float4* row = (const float4*)(emb + (size_t)k * DIM);
    float s = 0.f;
    #pragma unroll 4
    for (int i = 0; i < DIM / 4; ++i) {
        float4 v = row[i];
        s += v.x * v.x + v.y * v.y + v.z * v.z + v.w * v.w;
    }
    enorm[k] = s;
}

// ---------------- phase 1: fp32 distances + best2 argmin + tie worklist ----------------
__global__ __launch_bounds__(256) void argmin_kernel(const float* __restrict__ lat,
                                                     const float* __restrict__ emb,
                                                     const float* __restrict__ enorm,
                                                     int* __restrict__ inds,
                                                     int* __restrict__ counter,
                                                     int* __restrict__ list) {
    __shared__ float As[DSTEP][PAD_M];   // As[d][m]
    __shared__ float Bs[DSTEP][PAD_M];   // Bs[d][n]
    __shared__ float rbest[BM][17];
    __shared__ float rsec[BM][17];
    __shared__ int   ridx[BM][17];

    const int tid = threadIdx.x;
    const int tx = tid & 15;          // column group
    const int ty = tid >> 4;          // row group
    const int row0 = blockIdx.x * BM;

    const int lm  = tid >> 2;         // 0..63: which row/col this thread stages
    const int ld0 = (tid & 3) * 8;    // d offset for staging (8 floats)

    float best[4], sec[4];
    int bidx[4];
    #pragma unroll
    for (int i = 0; i < 4; ++i) { best[i] = INFINITY; sec[i] = INFINITY; bidx[i] = 0; }

    for (int ct = 0; ct < KC / BN; ++ct) {
        float acc[4][4];
        #pragma unroll
        for (int i = 0; i < 4; ++i)
            #pragma unroll
            for (int j = 0; j < 4; ++j) acc[i][j] = 0.f;

        for (int dc = 0; dc < DIM; dc += DSTEP) {
            const float* ap = lat + (size_t)(row0 + lm) * DIM + dc + ld0;
            float4 a0 = *(const float4*)ap;
            float4 a1 = *(const float4*)(ap + 4);
            As[ld0 + 0][lm] = a0.x; As[ld0 + 1][lm] = a0.y;
            As[ld0 + 2][lm] = a0.z; As[ld0 + 3][lm] = a0.w;
            As[ld0 + 4][lm] = a1.x; As[ld0 + 5][lm] = a1.y;
            As[ld0 + 6][lm] = a1.z; As[ld0 + 7][lm] = a1.w;
            const float* bp = emb + (size_t)(ct * BN + lm) * DIM + dc + ld0;
            float4 b0 = *(const float4*)bp;
            float4 b1 = *(const float4*)(bp + 4);
            Bs[ld0 + 0][lm] = b0.x; Bs[ld0 + 1][lm] = b0.y;
            Bs[ld0 + 2][lm] = b0.z; Bs[ld0 + 3][lm] = b0.w;
            Bs[ld0 + 4][lm] = b1.x; Bs[ld0 + 5][lm] = b1.y;
            Bs[ld0 + 6][lm] = b1.z; Bs[ld0 + 7][lm] = b1.w;
            __syncthreads();

            #pragma unroll
            for (int d = 0; d < DSTEP; ++d) {
                float4 av = *(const float4*)&As[d][ty * 4];
                float4 bv = *(const float4*)&Bs[d][tx * 4];
                float a[4] = {av.x, av.y, av.z, av.w};
                float b[4] = {bv.x, bv.y, bv.z, bv.w};
                #pragma unroll
                for (int i = 0; i < 4; ++i)
                    #pragma unroll
                    for (int j = 0; j < 4; ++j)
                        acc[i][j] = fmaf(a[i], b[j], acc[i][j]);
            }
            __syncthreads();
        }

        #pragma unroll
        for (int j = 0; j < 4; ++j) {
            int n = ct * BN + tx * 4 + j;
            float en = enorm[n];
            #pragma unroll
            for (int i = 0; i < 4; ++i) {
                float dist = fmaf(-2.f, acc[i][j], en);
                if (dist < best[i]) { sec[i] = best[i]; best[i] = dist; bidx[i] = n; }
                else if (dist < sec[i]) sec[i] = dist;
            }
        }
    }

    #pragma unroll
    for (int i = 0; i < 4; ++i) {
        rbest[ty * 4 + i][tx] = best[i];
        rsec [ty * 4 + i][tx] = sec[i];
        ridx [ty * 4 + i][tx] = bidx[i];
    }
    __syncthreads();
    if (tid < BM) {
        float g1 = INFINITY, g2 = INFINITY;
        int i1 = 0x7fffffff;
        for (int t = 0; t < 16; ++t) {
            float d = rbest[tid][t];
            float s = rsec[tid][t];
            int   ix = ridx[tid][t];
            if (d < g1 || (d == g1 && ix < i1)) {
                g2 = fminf(g2, g1);
                g1 = d; i1 = ix;
                g2 = fminf(g2, s);
            } else {
                g2 = fminf(g2, d);
            }
        }
        inds[row0 + tid] = i1;
        if (g2 - g1 <= EPS_MARGIN) {
            int p = atomicAdd(counter, 1);
            list[p] = row0 + tid;
        }
    }
}

// ---------------- phase 2: f64 refine, one block per tied row, K across threads ------
__global__ __launch_bounds__(256) void refine_kernel(const float* __restrict__ lat,
                                                     const float* __restrict__ emb,
                                                     const int* __restrict__ counter,
                                                     const int* __restrict__ list,
                                                     int* __restrict__ inds) {
    __shared__ double x2[DIM];     // 2*x
    __shared__ double bv[256];
    __shared__ int    bi[256];
    const int tid = threadIdx.x;
    const int cnt = *counter;

    for (int it = blockIdx.x; it < cnt; it += gridDim.x) {
        const int row = list[it];
        x2[tid] = 2.0 * (double)lat[(size_t)row * DIM + tid];
        __syncthreads();

        double acc[4] = {0.0, 0.0, 0.0, 0.0};    // k = kk*256 + tid
        for (int d = 0; d < DIM; d += 4) {
            double c0 = x2[d], c1 = x2[d + 1], c2 = x2[d + 2], c3 = x2[d + 3];
            #pragma unroll
            for (int kk = 0; kk < 4; ++kk) {
                const float4 ev = *(const float4*)(emb + (size_t)(kk * 256 + tid) * DIM + d);
                double e0 = ev.x, e1 = ev.y, e2 = ev.z, e3 = ev.w;
                acc[kk] += e0 * (e0 - c0) + e1 * (e1 - c1)
                         + e2 * (e2 - c2) + e3 * (e3 - c3);
            }
        }
        // per-thread best (ascending k order, strict < -> smallest k wins)
        double bestv = acc[0]; int besti = tid;
        #pragma unroll
        for (int kk = 1; kk < 4; ++kk) {
            if (acc[kk] < bestv) { bestv = acc[kk]; besti = kk * 256 + tid; }
        }
        bv[tid] = bestv; bi[tid] = besti;
        __syncthreads();
        for (int st = 128; st > 0; st >>= 1) {
            if (tid < st) {
                double ov = bv[tid + st]; int oi = bi[tid + st];
                if (ov < bv[tid] || (ov == bv[tid] && oi < bi[tid])) {
                    bv[tid] = ov; bi[tid] = oi;
                }
            }
            __syncthreads();
        }
        if (tid == 0) inds[row] = bi[0];
        __syncthreads();   // protect x2/bv/bi before next list entry
    }
}

// ---------------- histogram of codes ----------------
__global__ __launch_bounds__(256) void hist_kernel(const int* __restrict__ inds,
                                                   int* __restrict__ hist) {
    int r = blockIdx.x * 256 + threadIdx.x;
    if (r < N_ROWS) atomicAdd(&hist[inds[r]], 1);
}

// ---------------- gather + quantized_st + MSE partials ----------------
__global__ __launch_bounds__(256) void gather_kernel(const float* __restrict__ lat,
                                                     const float* __restrict__ emb,
                                                     const int* __restrict__ inds,
                                                     float* __restrict__ out,
                                                     double* __restrict__ partials) {
    __shared__ double wsum[4];
    const int tid = threadIdx.x;
    double acc = 0.0;
    const int nvec = N_ROWS * DIM / 4;
    for (int idx = blockIdx.x * blockDim.x + tid; idx < nvec; idx += gridDim.x * blockDim.x) {
        int row = idx >> 6;
        int dv = idx & 63;
        int k = inds[row];
        float4 xv = ((const float4*)lat)[idx];
        float4 qv = ((const float4*)(emb + (size_t)k * DIM))[dv];
        float d0 = qv.x - xv.x, d1 = qv.y - xv.y, d2 = qv.z - xv.z, d3 = qv.w - xv.w;
        float4 o;
        o.x = xv.x + d0; o.y = xv.y + d1; o.z = xv.z + d2; o.w = xv.w + d3;
        ((float4*)out)[idx] = o;
        acc += (double)d0 * d0 + (double)d1 * d1 + (double)d2 * d2 + (double)d3 * d3;
    }
    #pragma unroll
    for (int off = 32; off >= 1; off >>= 1) acc += __shfl_xor(acc, off);
    if ((tid & 63) == 0) wsum[tid >> 6] = acc;
    __syncthreads();
    if (tid == 0) partials[blockIdx.x] = wsum[0] + wsum[1] + wsum[2] + wsum[3];
}

// ---------------- finalize: vq_loss + perplexity ----------------
__global__ __launch_bounds__(256) void finalize_kernel(const int* __restrict__ hist,
                                                       const double* __restrict__ partials,
                                                       float* __restrict__ out_tail) {
    __shared__ double sh[256];
    const int tid = threadIdx.x;
    double s = 0.0;
    for (int i = tid; i < 2048; i += 256) s += partials[i];
    sh[tid] = s; __syncthreads();
    for (int st = 128; st > 0; st >>= 1) {
        if (tid < st) sh[tid] += sh[tid + st];
        __syncthreads();
    }
    double sumsq = sh[0];
    __syncthreads();

    double e = 0.0;
    for (int k = tid; k < KC; k += 256) {
        double p = (double)hist[k] / (double)N_ROWS;
        e += p * log(p + 1e-10);
    }
    sh[tid] = e; __syncthreads();
    for (int st = 128; st > 0; st >>= 1) {
        if (tid < st) sh[tid] += sh[tid + st];
        __syncthreads();
    }
    if (tid == 0) {
        double mse = sumsq / (double)((size_t)N_ROWS * DIM);
        out_tail[0] = (float)(1.25 * mse);
        out_tail[1] = (float)exp(-sh[0]);
    }
}

extern "C" void kernel_launch(void* const* d_in, const int* in_sizes, int n_in,
                              void* d_out, int out_size, void* d_ws, size_t ws_size,
                              hipStream_t stream) {
    const float* lat = (const float*)d_in[0];
    const float* emb = (const float*)d_in[1];
    float* out = (float*)d_out;

    char* ws = (char*)d_ws;
    int*    hist     = (int*)(ws);                                  // 4 KB
    float*  enorm    = (float*)(ws + 4096);                         // 4 KB
    int*    inds     = (int*)(ws + 8192);                           // 128 KB
    int*    counter  = (int*)(ws + 8192 + 131072);                  // 256 B slot
    int*    list     = (int*)(ws + 8192 + 131072 + 256);            // 128 KB
    double* partials = (double*)(ws + 8192 + 131072 + 256 + 131072);// 16 KB

    hipMemsetAsync(hist, 0, KC * sizeof(int), stream);
    hipMemsetAsync(counter, 0, sizeof(int), stream);
    enorm_kernel<<<KC / 256, 256, 0, stream>>>(emb, enorm);
    argmin_kernel<<<N_ROWS / BM, 256, 0, stream>>>(lat, emb, enorm, inds, counter, list);
    refine_kernel<<<256, 256, 0, stream>>>(lat, emb, counter, list, inds);
    hist_kernel<<<N_ROWS / 256, 256, 0, stream>>>(inds, hist);
    gather_kernel<<<2048, 256, 0, stream>>>(lat, emb, inds, out, partials);
    finalize_kernel<<<1, 256, 0, stream>>>(hist, partials, out + (size_t)N_ROWS * DIM);
}

// Round 3
// 290.564 us; speedup vs baseline: 6.2402x; 1.7069x over previous
//
#include <hip/hip_runtime.h>
#include <math.h>

#define N_ROWS 32768
#define DIM    256
#define KC     1024
#define BM     64
#define BN     64
#define DSTEP  32
#define PAD_M  68
#define EPS_MARGIN 1e-4f

typedef unsigned short u16;
typedef __attribute__((ext_vector_type(8))) short short8;
typedef __attribute__((ext_vector_type(4))) float f32x4;

// ---------------- codebook squared norms ----------------
__global__ __launch_bounds__(256) void enorm_kernel(const float* __restrict__ emb,
                                                    float* __restrict__ enorm) {
    int k = blockIdx.x * blockDim.x + threadIdx.x;
    if (k >= KC) return;
    const float4* row = (const float4*)(emb + (size_t)k * DIM);
    float s = 0.f;
    #pragma unroll 4
    for (int i = 0; i < DIM / 4; ++i) {
        float4 v = row[i];
        s += v.x * v.x + v.y * v.y + v.z * v.z + v.w * v.w;
    }
    enorm[k] = s;
}

// ---------------- split f32 -> bf16 hi + bf16 lo (RNE) ----------------
__global__ __launch_bounds__(256) void split_kernel(const float* __restrict__ in,
                                                    u16* __restrict__ hi,
                                                    u16* __restrict__ lo, int n4) {
    for (int i = blockIdx.x * blockDim.x + threadIdx.x; i < n4;
         i += gridDim.x * blockDim.x) {
        float4 v = ((const float4*)in)[i];
        float f[4] = {v.x, v.y, v.z, v.w};
        u16 hh[4], ll[4];
        #pragma unroll
        for (int j = 0; j < 4; ++j) {
            unsigned u = __float_as_uint(f[j]);
            unsigned hb = (u + 0x7fffu + ((u >> 16) & 1u)) >> 16;
            hh[j] = (u16)hb;
            float r = f[j] - __uint_as_float(hb << 16);
            unsigned u2 = __float_as_uint(r);
            unsigned lb = (u2 + 0x7fffu + ((u2 >> 16) & 1u)) >> 16;
            ll[j] = (u16)lb;
        }
        ushort4 hv; hv.x = hh[0]; hv.y = hh[1]; hv.z = hh[2]; hv.w = hh[3];
        ushort4 lv; lv.x = ll[0]; lv.y = ll[1]; lv.z = ll[2]; lv.w = ll[3];
        ((ushort4*)hi)[i] = hv;
        ((ushort4*)lo)[i] = lv;
    }
}

// ---------------- MFMA split-bf16 distance + per-colblock best2 ----------------
// K-extended GEMM: [xh|xh|xl] . [eh|el|eh], 12 K-tiles of 64.
// LDS tiles [128][64] bf16 with st-16B XOR swizzle: phys_chunk = log_chunk ^ (row&7),
// realized via pre-swizzled global source (global_load_lds writes linearly).
__global__ __launch_bounds__(256) void mfma_argmin_kernel(
        const u16* __restrict__ xh, const u16* __restrict__ xl,
        const u16* __restrict__ eh, const u16* __restrict__ el,
        const float* __restrict__ enorm,
        float2* __restrict__ resv, int* __restrict__ resi) {
    __shared__ u16 Ablk[128 * 64];
    __shared__ u16 Bblk[128 * 64];
    __shared__ float ep_b[128][2];
    __shared__ float ep_s[128][2];
    __shared__ int   ep_i[128][2];

    const int tid = threadIdx.x;
    const int l   = tid & 63;
    const int w   = tid >> 6;
    const int wr  = w >> 1, wc = w & 1;
    const size_t row0 = (size_t)blockIdx.x * 128;
    const int    col0 = blockIdx.y * 128;

    f32x4 acc[4][4];
    #pragma unroll
    for (int a = 0; a < 4; ++a)
        #pragma unroll
        for (int b = 0; b < 4; ++b)
            acc[a][b] = (f32x4){0.f, 0.f, 0.f, 0.f};

    const int srow   = l >> 3;            // row within 8-row group
    const int gchunk = (l & 7) ^ srow;    // pre-swizzled global 16B-chunk index

    for (int t = 0; t < 12; ++t) {
        const int pass = t >> 2;
        const int kk0  = (t & 3) * 64;
        const u16* Asrc = (pass < 2) ? xh : xl;
        const u16* Bsrc = (pass == 1) ? el : eh;
        if (t) __syncthreads();
        #pragma unroll
        for (int i = 0; i < 4; ++i) {
            const int rbase = w * 32 + i * 8;
            const u16* ga = Asrc + (row0 + rbase + srow) * 256 + kk0 + gchunk * 8;
            __builtin_amdgcn_global_load_lds(
                (const __attribute__((address_space(1))) void*)ga,
                (__attribute__((address_space(3))) void*)&Ablk[rbase * 64], 16, 0, 0);
            const u16* gb = Bsrc + (size_t)(col0 + rbase + srow) * 256 + kk0 + gchunk * 8;
            __builtin_amdgcn_global_load_lds(
                (const __attribute__((address_space(1))) void*)gb,
                (__attribute__((address_space(3))) void*)&Bblk[rbase * 64], 16, 0, 0);
        }
        __syncthreads();
        #pragma unroll
        for (int ks = 0; ks < 2; ++ks) {
            short8 af[4], bf[4];
            #pragma unroll
            for (int mf = 0; mf < 4; ++mf) {
                const int r  = wr * 64 + mf * 16 + (l & 15);
                const int ch = (ks * 4 + (l >> 4)) ^ (r & 7);
                af[mf] = *(const short8*)&Ablk[r * 64 + ch * 8];
            }
            #pragma unroll
            for (int nf = 0; nf < 4; ++nf) {
                const int r  = wc * 64 + nf * 16 + (l & 15);
                const int ch = (ks * 4 + (l >> 4)) ^ (r & 7);
                bf[nf] = *(const short8*)&Bblk[r * 64 + ch * 8];
            }
            #pragma unroll
            for (int mf = 0; mf < 4; ++mf)
                #pragma unroll
                for (int nf = 0; nf < 4; ++nf)
                    acc[mf][nf] = __builtin_amdgcn_mfma_f32_16x16x32_bf16(
                        af[mf], bf[nf], acc[mf][nf], 0, 0, 0);
        }
    }

    // epilogue: dist = enorm[n] - 2*dot ; per-row best2 within this col-block
    const int lcol  = l & 15;
    const int lrow4 = (l >> 4) * 4;
    float en[4]; int ncol[4];
    #pragma unroll
    for (int nf = 0; nf < 4; ++nf) {
        ncol[nf] = col0 + wc * 64 + nf * 16 + lcol;
        en[nf]   = enorm[ncol[nf]];
    }
    #pragma unroll
    for (int mf = 0; mf < 4; ++mf) {
        #pragma unroll
        for (int r = 0; r < 4; ++r) {
            float b = INFINITY, s = INFINITY; int bi = 0;
            #pragma unroll
            for (int nf = 0; nf < 4; ++nf) {
                float d = fmaf(-2.f, acc[mf][nf][r], en[nf]);
                if (d < b) { s = b; b = d; bi = ncol[nf]; }
                else s = fminf(s, d);
            }
            #pragma unroll
            for (int m = 1; m < 16; m <<= 1) {
                float b2 = __shfl_xor(b, m);
                float s2 = __shfl_xor(s, m);
                int   i2 = __shfl_xor(bi, m);
                if (b2 < b) { s = fminf(b, s2); b = b2; bi = i2; }
                else s = fminf(s, b2);
            }
            if (lcol == 0) {
                const int rr = wr * 64 + mf * 16 + lrow4 + r;
                ep_b[rr][wc] = b; ep_s[rr][wc] = s; ep_i[rr][wc] = bi;
            }
        }
    }
    __syncthreads();
    if (tid < 128) {
        float b = ep_b[tid][0], s = ep_s[tid][0]; int bi = ep_i[tid][0];
        float b2 = ep_b[tid][1], s2 = ep_s[tid][1]; int i2 = ep_i[tid][1];
        if (b2 < b) { s = fminf(b, s2); b = b2; bi = i2; }
        else s = fminf(s, fminf(b2, s2));
        const size_t o = (row0 + tid) * 8 + blockIdx.y;
        resv[o] = make_float2(b, s);
        resi[o] = bi;
    }
}

// ---------------- combine col-blocks -> inds + tie worklist ----------------
__global__ __launch_bounds__(256) void combine_kernel(const float2* __restrict__ resv,
                                                      const int* __restrict__ resi,
                                                      int* __restrict__ inds,
                                                      int* __restrict__ counter,
                                                      int* __restrict__ list) {
    const int row = blockIdx.x * 256 + threadIdx.x;
    float b = INFINITY, s = INFINITY; int bi = 0;
    #pragma unroll
    for (int c = 0; c < 8; ++c) {
        float2 v = resv[(size_t)row * 8 + c];
        int i2 = resi[(size_t)row * 8 + c];
        if (v.x < b) { s = fminf(b, v.y); b = v.x; bi = i2; }
        else s = fminf(s, fminf(v.x, v.y));
    }
    inds[row] = bi;
    if (s - b <= EPS_MARGIN) {
        int p = atomicAdd(counter, 1);
        list[p] = row;
    }
}

// ---------------- fallback fp32 argmin (used if ws too small) ----------------
__global__ __launch_bounds__(256) void argmin_kernel(const float* __restrict__ lat,
                                                     const float* __restrict__ emb,
                                                     const float* __restrict__ enorm,
                                                     int* __restrict__ inds,
                                                     int* __restrict__ counter,
                                                     int* __restrict__ list) {
    __shared__ float As[DSTEP][PAD_M];
    __shared__ float Bs[DSTEP][PAD_M];
    __shared__ float rbest[BM][17];
    __shared__ float rsec[BM][17];
    __shared__ int   ridx[BM][17];

    const int tid = threadIdx.x;
    const int tx = tid & 15;
    const int ty = tid >> 4;
    const int row0 = blockIdx.x * BM;
    const int lm  = tid >> 2;
    const int ld0 = (tid & 3) * 8;

    float best[4], sec[4];
    int bidx[4];
    #pragma unroll
    for (int i = 0; i < 4; ++i) { best[i] = INFINITY; sec[i] = INFINITY; bidx[i] = 0; }

    for (int ct = 0; ct < KC / BN; ++ct) {
        float acc[4][4];
        #pragma unroll
        for (int i = 0; i < 4; ++i)
            #pragma unroll
            for (int j = 0; j < 4; ++j) acc[i][j] = 0.f;

        for (int dc = 0; dc < DIM; dc += DSTEP) {
            const float* ap = lat + (size_t)(row0 + lm) * DIM + dc + ld0;
            float4 a0 = *(const float4*)ap;
            float4 a1 = *(const float4*)(ap + 4);
            As[ld0 + 0][lm] = a0.x; As[ld0 + 1][lm] = a0.y;
            As[ld0 + 2][lm] = a0.z; As[ld0 + 3][lm] = a0.w;
            As[ld0 + 4][lm] = a1.x; As[ld0 + 5][lm] = a1.y;
            As[ld0 + 6][lm] = a1.z; As[ld0 + 7][lm] = a1.w;
            const float* bp = emb + (size_t)(ct * BN + lm) * DIM + dc + ld0;
            float4 b0 = *(const float4*)bp;
            float4 b1 = *(const float4*)(bp + 4);
            Bs[ld0 + 0][lm] = b0.x; Bs[ld0 + 1][lm] = b0.y;
            Bs[ld0 + 2][lm] = b0.z; Bs[ld0 + 3][lm] = b0.w;
            Bs[ld0 + 4][lm] = b1.x; Bs[ld0 + 5][lm] = b1.y;
            Bs[ld0 + 6][lm] = b1.z; Bs[ld0 + 7][lm] = b1.w;
            __syncthreads();
            #pragma unroll
            for (int d = 0; d < DSTEP; ++d) {
                float4 av = *(const float4*)&As[d][ty * 4];
                float4 bv = *(const float4*)&Bs[d][tx * 4];
                float a[4] = {av.x, av.y, av.z, av.w};
                float b[4] = {bv.x, bv.y, bv.z, bv.w};
                #pragma unroll
                for (int i = 0; i < 4; ++i)
                    #pragma unroll
                    for (int j = 0; j < 4; ++j)
                        acc[i][j] = fmaf(a[i], b[j], acc[i][j]);
            }
            __syncthreads();
        }
        #pragma unroll
        for (int j = 0; j < 4; ++j) {
            int n = ct * BN + tx * 4 + j;
            float en = enorm[n];
            #pragma unroll
            for (int i = 0; i < 4; ++i) {
                float dist = fmaf(-2.f, acc[i][j], en);
                if (dist < best[i]) { sec[i] = best[i]; best[i] = dist; bidx[i] = n; }
                else if (dist < sec[i]) sec[i] = dist;
            }
        }
    }
    #pragma unroll
    for (int i = 0; i < 4; ++i) {
        rbest[ty * 4 + i][tx] = best[i];
        rsec [ty * 4 + i][tx] = sec[i];
        ridx [ty * 4 + i][tx] = bidx[i];
    }
    __syncthreads();
    if (tid < BM) {
        float g1 = INFINITY, g2 = INFINITY;
        int i1 = 0x7fffffff;
        for (int t = 0; t < 16; ++t) {
            float d = rbest[tid][t];
            float s = rsec[tid][t];
            int   ix = ridx[tid][t];
            if (d < g1 || (d == g1 && ix < i1)) {
                g2 = fminf(g2, g1);
                g1 = d; i1 = ix;
                g2 = fminf(g2, s);
            } else {
                g2 = fminf(g2, d);
            }
        }
        inds[row0 + tid] = i1;
        if (g2 - g1 <= EPS_MARGIN) {
            int p = atomicAdd(counter, 1);
            list[p] = row0 + tid;
        }
    }
}

// ---------------- f64 refine, one block per tied row ----------------
__global__ __launch_bounds__(256) void refine_kernel(const float* __restrict__ lat,
                                                     const float* __restrict__ emb,
                                                     const int* __restrict__ counter,
                                                     const int* __restrict__ list,
                                                     int* __restrict__ inds) {
    __shared__ double x2[DIM];
    __shared__ double bv[256];
    __shared__ int    bi[256];
    const int tid = threadIdx.x;
    const int cnt = *counter;

    for (int it = blockIdx.x; it < cnt; it += gridDim.x) {
        const int row = list[it];
        x2[tid] = 2.0 * (double)lat[(size_t)row * DIM + tid];
        __syncthreads();
        double acc[4] = {0.0, 0.0, 0.0, 0.0};
        for (int d = 0; d < DIM; d += 4) {
            double c0 = x2[d], c1 = x2[d + 1], c2 = x2[d + 2], c3 = x2[d + 3];
            #pragma unroll
            for (int kk = 0; kk < 4; ++kk) {
                const float4 ev = *(const float4*)(emb + (size_t)(kk * 256 + tid) * DIM + d);
                double e0 = ev.x, e1 = ev.y, e2 = ev.z, e3 = ev.w;
                acc[kk] += e0 * (e0 - c0) + e1 * (e1 - c1)
                         + e2 * (e2 - c2) + e3 * (e3 - c3);
            }
        }
        double bestv = acc[0]; int besti = tid;
        #pragma unroll
        for (int kk = 1; kk < 4; ++kk) {
            if (acc[kk] < bestv) { bestv = acc[kk]; besti = kk * 256 + tid; }
        }
        bv[tid] = bestv; bi[tid] = besti;
        __syncthreads();
        for (int st = 128; st > 0; st >>= 1) {
            if (tid < st) {
                double ov = bv[tid + st]; int oi = bi[tid + st];
                if (ov < bv[tid] || (ov == bv[tid] && oi < bi[tid])) {
                    bv[tid] = ov; bi[tid] = oi;
                }
            }
            __syncthreads();
        }
        if (tid == 0) inds[row] = bi[0];
        __syncthreads();
    }
}

// ---------------- histogram ----------------
__global__ __launch_bounds__(256) void hist_kernel(const int* __restrict__ inds,
                                                   int* __restrict__ hist) {
    int r = blockIdx.x * 256 + threadIdx.x;
    if (r < N_ROWS) atomicAdd(&hist[inds[r]], 1);
}

// ---------------- gather + quantized_st + MSE partials ----------------
__global__ __launch_bounds__(256) void gather_kernel(const float* __restrict__ lat,
                                                     const float* __restrict__ emb,
                                                     const int* __restrict__ inds,
                                                     float* __restrict__ out,
                                                     double* __restrict__ partials) {
    __shared__ double wsum[4];
    const int tid = threadIdx.x;
    double acc = 0.0;
    const int nvec = N_ROWS * DIM / 4;
    for (int idx = blockIdx.x * blockDim.x + tid; idx < nvec; idx += gridDim.x * blockDim.x) {
        int row = idx >> 6;
        int dv = idx & 63;
        int k = inds[row];
        float4 xv = ((const float4*)lat)[idx];
        float4 qv = ((const float4*)(emb + (size_t)k * DIM))[dv];
        float d0 = qv.x - xv.x, d1 = qv.y - xv.y, d2 = qv.z - xv.z, d3 = qv.w - xv.w;
        float4 o;
        o.x = xv.x + d0; o.y = xv.y + d1; o.z = xv.z + d2; o.w = xv.w + d3;
        ((float4*)out)[idx] = o;
        acc += (double)d0 * d0 + (double)d1 * d1 + (double)d2 * d2 + (double)d3 * d3;
    }
    #pragma unroll
    for (int off = 32; off >= 1; off >>= 1) acc += __shfl_xor(acc, off);
    if ((tid & 63) == 0) wsum[tid >> 6] = acc;
    __syncthreads();
    if (tid == 0) partials[blockIdx.x] = wsum[0] + wsum[1] + wsum[2] + wsum[3];
}

// ---------------- finalize ----------------
__global__ __launch_bounds__(256) void finalize_kernel(const int* __restrict__ hist,
                                                       const double* __restrict__ partials,
                                                       float* __restrict__ out_tail) {
    __shared__ double sh[256];
    const int tid = threadIdx.x;
    double s = 0.0;
    for (int i = tid; i < 2048; i += 256) s += partials[i];
    sh[tid] = s; __syncthreads();
    for (int st = 128; st > 0; st >>= 1) {
        if (tid < st) sh[tid] += sh[tid + st];
        __syncthreads();
    }
    double sumsq = sh[0];
    __syncthreads();
    double e = 0.0;
    for (int k = tid; k < KC; k += 256) {
        double p = (double)hist[k] / (double)N_ROWS;
        e += p * log(p + 1e-10);
    }
    sh[tid] = e; __syncthreads();
    for (int st = 128; st > 0; st >>= 1) {
        if (tid < st) sh[tid] += sh[tid + st];
        __syncthreads();
    }
    if (tid == 0) {
        double mse = sumsq / (double)((size_t)N_ROWS * DIM);
        out_tail[0] = (float)(1.25 * mse);
        out_tail[1] = (float)exp(-sh[0]);
    }
}

extern "C" void kernel_launch(void* const* d_in, const int* in_sizes, int n_in,
                              void* d_out, int out_size, void* d_ws, size_t ws_size,
                              hipStream_t stream) {
    const float* lat = (const float*)d_in[0];
    const float* emb = (const float*)d_in[1];
    float* out = (float*)d_out;

    char* ws = (char*)d_ws;
    int*    hist     = (int*)(ws);                    // 4 KB
    float*  enorm    = (float*)(ws + 4096);           // 4 KB
    int*    inds     = (int*)(ws + 8192);             // 128 KB
    int*    counter  = (int*)(ws + 139264);           // 256 B
    int*    list     = (int*)(ws + 139520);           // 128 KB
    double* partials = (double*)(ws + 270592);        // 16 KB
    float2* resv     = (float2*)(ws + 286976);        // 2 MB
    int*    resi     = (int*)(ws + 2384128);          // 1 MB
    u16*    eh       = (u16*)(ws + 3432704);          // 512 KB
    u16*    el       = (u16*)(ws + 3956992);          // 512 KB
    const size_t WS_NEED = 4481280;

    hipMemsetAsync(hist, 0, KC * sizeof(int), stream);
    hipMemsetAsync(counter, 0, sizeof(int), stream);
    enorm_kernel<<<KC / 256, 256, 0, stream>>>(emb, enorm);

    if (ws_size >= WS_NEED) {
        // d_out doubles as scratch for split-x until gather overwrites it
        u16* xh = (u16*)out;
        u16* xl = xh + (size_t)N_ROWS * DIM;
        split_kernel<<<1024, 256, 0, stream>>>(lat, xh, xl, N_ROWS * DIM / 4);
        split_kernel<<<64, 256, 0, stream>>>(emb, eh, el, KC * DIM / 4);
        dim3 grid(N_ROWS / 128, KC / 128);
        mfma_argmin_kernel<<<grid, 256, 0, stream>>>(xh, xl, eh, el, enorm, resv, resi);
        combine_kernel<<<N_ROWS / 256, 256, 0, stream>>>(resv, resi, inds, counter, list);
    } else {
        argmin_kernel<<<N_ROWS / BM, 256, 0, stream>>>(lat, emb, enorm, inds, counter, list);
    }
    refine_kernel<<<256, 256, 0, stream>>>(lat, emb, counter, list, inds);
    hist_kernel<<<N_ROWS / 256, 256, 0, stream>>>(inds, hist);
    gather_kernel<<<2048, 256, 0, stream>>>(lat, emb, inds, out, partials);
    finalize_kernel<<<1, 256, 0, stream>>>(hist, partials, out + (size_t)N_ROWS * DIM);
}

// Round 4
// 128.032 us; speedup vs baseline: 14.1619x; 2.2695x over previous
//
#include <hip/hip_runtime.h>
#include <math.h>

#define N_ROWS 32768
#define DIM    256
#define KC     1024
#define BM     64
#define BN     64
#define DSTEP  32
#define PAD_M  68

typedef unsigned short u16;
typedef __attribute__((ext_vector_type(8))) short short8;
typedef __attribute__((ext_vector_type(4))) float f32x4;

// ---------------- codebook squared norms ----------------
__global__ __launch_bounds__(256) void enorm_kernel(const float* __restrict__ emb,
                                                    float* __restrict__ enorm) {
    int k = blockIdx.x * blockDim.x + threadIdx.x;
    if (k >= KC) return;
    const float4* row = (const float4*)(emb + (size_t)k * DIM);
    float s = 0.f;
    #pragma unroll 4
    for (int i = 0; i < DIM / 4; ++i) {
        float4 v = row[i];
        s += v.x * v.x + v.y * v.y + v.z * v.z + v.w * v.w;
    }
    enorm[k] = s;
}

// ---------------- split f32 -> bf16 hi + bf16 lo (RNE) ----------------
__global__ __launch_bounds__(256) void split_kernel(const float* __restrict__ in,
                                                    u16* __restrict__ hi,
                                                    u16* __restrict__ lo, int n4) {
    for (int i = blockIdx.x * blockDim.x + threadIdx.x; i < n4;
         i += gridDim.x * blockDim.x) {
        float4 v = ((const float4*)in)[i];
        float f[4] = {v.x, v.y, v.z, v.w};
        u16 hh[4], ll[4];
        #pragma unroll
        for (int j = 0; j < 4; ++j) {
            unsigned u = __float_as_uint(f[j]);
            unsigned hb = (u + 0x7fffu + ((u >> 16) & 1u)) >> 16;
            hh[j] = (u16)hb;
            float r = f[j] - __uint_as_float(hb << 16);
            unsigned u2 = __float_as_uint(r);
            unsigned lb = (u2 + 0x7fffu + ((u2 >> 16) & 1u)) >> 16;
            ll[j] = (u16)lb;
        }
        ushort4 hv; hv.x = hh[0]; hv.y = hh[1]; hv.z = hh[2]; hv.w = hh[3];
        ushort4 lv; lv.x = ll[0]; lv.y = ll[1]; lv.z = ll[2]; lv.w = ll[3];
        ((ushort4*)hi)[i] = hv;
        ((ushort4*)lo)[i] = lv;
    }
}

// ---------------- MFMA split-bf16 distance + per-colblock best ----------------
// K-extended GEMM: [xh|xh|xl] . [eh|el|eh], 12 K-tiles of 64.
// LDS tiles [128][64] bf16, st-16B XOR swizzle realized via pre-swizzled global src.
__global__ __launch_bounds__(256) void mfma_argmin_kernel(
        const u16* __restrict__ xh, const u16* __restrict__ xl,
        const u16* __restrict__ eh, const u16* __restrict__ el,
        const float* __restrict__ enorm,
        float* __restrict__ resv, int* __restrict__ resi) {
    __shared__ u16 Ablk[128 * 64];
    __shared__ u16 Bblk[128 * 64];
    __shared__ float ep_b[128][2];
    __shared__ int   ep_i[128][2];

    const int tid = threadIdx.x;
    const int l   = tid & 63;
    const int w   = tid >> 6;
    const int wr  = w >> 1, wc = w & 1;
    const size_t row0 = (size_t)blockIdx.x * 128;
    const int    col0 = blockIdx.y * 128;

    f32x4 acc[4][4];
    #pragma unroll
    for (int a = 0; a < 4; ++a)
        #pragma unroll
        for (int b = 0; b < 4; ++b)
            acc[a][b] = (f32x4){0.f, 0.f, 0.f, 0.f};

    const int srow   = l >> 3;            // row within 8-row group
    const int gchunk = (l & 7) ^ srow;    // pre-swizzled global 16B-chunk index

    for (int t = 0; t < 12; ++t) {
        const int pass = t >> 2;
        const int kk0  = (t & 3) * 64;
        const u16* Asrc = (pass < 2) ? xh : xl;
        const u16* Bsrc = (pass == 1) ? el : eh;
        if (t) __syncthreads();
        #pragma unroll
        for (int i = 0; i < 4; ++i) {
            const int rbase = w * 32 + i * 8;
            const u16* ga = Asrc + (row0 + rbase + srow) * 256 + kk0 + gchunk * 8;
            __builtin_amdgcn_global_load_lds(
                (const __attribute__((address_space(1))) void*)ga,
                (__attribute__((address_space(3))) void*)&Ablk[rbase * 64], 16, 0, 0);
            const u16* gb = Bsrc + (size_t)(col0 + rbase + srow) * 256 + kk0 + gchunk * 8;
            __builtin_amdgcn_global_load_lds(
                (const __attribute__((address_space(1))) void*)gb,
                (__attribute__((address_space(3))) void*)&Bblk[rbase * 64], 16, 0, 0);
        }
        __syncthreads();
        #pragma unroll
        for (int ks = 0; ks < 2; ++ks) {
            short8 af[4], bf[4];
            #pragma unroll
            for (int mf = 0; mf < 4; ++mf) {
                const int r  = wr * 64 + mf * 16 + (l & 15);
                const int ch = (ks * 4 + (l >> 4)) ^ (r & 7);
                af[mf] = *(const short8*)&Ablk[r * 64 + ch * 8];
            }
            #pragma unroll
            for (int nf = 0; nf < 4; ++nf) {
                const int r  = wc * 64 + nf * 16 + (l & 15);
                const int ch = (ks * 4 + (l >> 4)) ^ (r & 7);
                bf[nf] = *(const short8*)&Bblk[r * 64 + ch * 8];
            }
            #pragma unroll
            for (int mf = 0; mf < 4; ++mf)
                #pragma unroll
                for (int nf = 0; nf < 4; ++nf)
                    acc[mf][nf] = __builtin_amdgcn_mfma_f32_16x16x32_bf16(
                        af[mf], bf[nf], acc[mf][nf], 0, 0, 0);
        }
    }

    // epilogue: dist = enorm[n] - 2*dot ; per-row best within this col-block
    const int lcol  = l & 15;
    const int lrow4 = (l >> 4) * 4;
    float en[4]; int ncol[4];
    #pragma unroll
    for (int nf = 0; nf < 4; ++nf) {
        ncol[nf] = col0 + wc * 64 + nf * 16 + lcol;
        en[nf]   = enorm[ncol[nf]];
    }
    #pragma unroll
    for (int mf = 0; mf < 4; ++mf) {
        #pragma unroll
        for (int r = 0; r < 4; ++r) {
            float b = INFINITY; int bi = 0;
            #pragma unroll
            for (int nf = 0; nf < 4; ++nf) {
                float d = fmaf(-2.f, acc[mf][nf][r], en[nf]);
                if (d < b) { b = d; bi = ncol[nf]; }
            }
            #pragma unroll
            for (int m = 1; m < 16; m <<= 1) {
                float b2 = __shfl_xor(b, m);
                int   i2 = __shfl_xor(bi, m);
                if (b2 < b || (b2 == b && i2 < bi)) { b = b2; bi = i2; }
            }
            if (lcol == 0) {
                const int rr = wr * 64 + mf * 16 + lrow4 + r;
                ep_b[rr][wc] = b; ep_i[rr][wc] = bi;
            }
        }
    }
    __syncthreads();
    if (tid < 128) {
        float b = ep_b[tid][0]; int bi = ep_i[tid][0];
        float b2 = ep_b[tid][1]; int i2 = ep_i[tid][1];
        if (b2 < b || (b2 == b && i2 < bi)) { b = b2; bi = i2; }
        const size_t o = (row0 + tid) * 8 + blockIdx.y;
        resv[o] = b;
        resi[o] = bi;
    }
}

// ---------------- combine col-blocks -> inds ----------------
__global__ __launch_bounds__(256) void combine_kernel(const float* __restrict__ resv,
                                                      const int* __restrict__ resi,
                                                      int* __restrict__ inds) {
    const int row = blockIdx.x * 256 + threadIdx.x;
    float b = INFINITY; int bi = 0x7fffffff;
    #pragma unroll
    for (int c = 0; c < 8; ++c) {
        float v = resv[(size_t)row * 8 + c];
        int i2 = resi[(size_t)row * 8 + c];
        if (v < b || (v == b && i2 < bi)) { b = v; bi = i2; }
    }
    inds[row] = bi;
}

// ---------------- fallback fp32 argmin (used if ws too small) ----------------
__global__ __launch_bounds__(256) void argmin_kernel(const float* __restrict__ lat,
                                                     const float* __restrict__ emb,
                                                     const float* __restrict__ enorm,
                                                     int* __restrict__ inds) {
    __shared__ float As[DSTEP][PAD_M];
    __shared__ float Bs[DSTEP][PAD_M];
    __shared__ float rbest[BM][17];
    __shared__ int   ridx[BM][17];

    const int tid = threadIdx.x;
    const int tx = tid & 15;
    const int ty = tid >> 4;
    const int row0 = blockIdx.x * BM;
    const int lm  = tid >> 2;
    const int ld0 = (tid & 3) * 8;

    float best[4];
    int bidx[4];
    #pragma unroll
    for (int i = 0; i < 4; ++i) { best[i] = INFINITY; bidx[i] = 0; }

    for (int ct = 0; ct < KC / BN; ++ct) {
        float acc[4][4];
        #pragma unroll
        for (int i = 0; i < 4; ++i)
            #pragma unroll
            for (int j = 0; j < 4; ++j) acc[i][j] = 0.f;

        for (int dc = 0; dc < DIM; dc += DSTEP) {
            const float* ap = lat + (size_t)(row0 + lm) * DIM + dc + ld0;
            float4 a0 = *(const float4*)ap;
            float4 a1 = *(const float4*)(ap + 4);
            As[ld0 + 0][lm] = a0.x; As[ld0 + 1][lm] = a0.y;
            As[ld0 + 2][lm] = a0.z; As[ld0 + 3][lm] = a0.w;
            As[ld0 + 4][lm] = a1.x; As[ld0 + 5][lm] = a1.y;
            As[ld0 + 6][lm] = a1.z; As[ld0 + 7][lm] = a1.w;
            const float* bp = emb + (size_t)(ct * BN + lm) * DIM + dc + ld0;
            float4 b0 = *(const float4*)bp;
            float4 b1 = *(const float4*)(bp + 4);
            Bs[ld0 + 0][lm] = b0.x; Bs[ld0 + 1][lm] = b0.y;
            Bs[ld0 + 2][lm] = b0.z; Bs[ld0 + 3][lm] = b0.w;
            Bs[ld0 + 4][lm] = b1.x; Bs[ld0 + 5][lm] = b1.y;
            Bs[ld0 + 6][lm] = b1.z; Bs[ld0 + 7][lm] = b1.w;
            __syncthreads();
            #pragma unroll
            for (int d = 0; d < DSTEP; ++d) {
                float4 av = *(const float4*)&As[d][ty * 4];
                float4 bv = *(const float4*)&Bs[d][tx * 4];
                float a[4] = {av.x, av.y, av.z, av.w};
                float b[4] = {bv.x, bv.y, bv.z, bv.w};
                #pragma unroll
                for (int i = 0; i < 4; ++i)
                    #pragma unroll
                    for (int j = 0; j < 4; ++j)
                        acc[i][j] = fmaf(a[i], b[j], acc[i][j]);
            }
            __syncthreads();
        }
        #pragma unroll
        for (int j = 0; j < 4; ++j) {
            int n = ct * BN + tx * 4 + j;
            float en = enorm[n];
            #pragma unroll
            for (int i = 0; i < 4; ++i) {
                float dist = fmaf(-2.f, acc[i][j], en);
                if (dist < best[i]) { best[i] = dist; bidx[i] = n; }
            }
        }
    }
    #pragma unroll
    for (int i = 0; i < 4; ++i) {
        rbest[ty * 4 + i][tx] = best[i];
        ridx [ty * 4 + i][tx] = bidx[i];
    }
    __syncthreads();
    if (tid < BM) {
        float g1 = INFINITY;
        int i1 = 0x7fffffff;
        for (int t = 0; t < 16; ++t) {
            float d = rbest[tid][t];
            int   ix = ridx[tid][t];
            if (d < g1 || (d == g1 && ix < i1)) { g1 = d; i1 = ix; }
        }
        inds[row0 + tid] = i1;
    }
}

// ---------------- histogram ----------------
__global__ __launch_bounds__(256) void hist_kernel(const int* __restrict__ inds,
                                                   int* __restrict__ hist) {
    int r = blockIdx.x * 256 + threadIdx.x;
    if (r < N_ROWS) atomicAdd(&hist[inds[r]], 1);
}

// ---------------- gather + quantized_st + MSE partials ----------------
__global__ __launch_bounds__(256) void gather_kernel(const float* __restrict__ lat,
                                                     const float* __restrict__ emb,
                                                     const int* __restrict__ inds,
                                                     float* __restrict__ out,
                                                     double* __restrict__ partials) {
    __shared__ double wsum[4];
    const int tid = threadIdx.x;
    double acc = 0.0;
    const int nvec = N_ROWS * DIM / 4;
    for (int idx = blockIdx.x * blockDim.x + tid; idx < nvec; idx += gridDim.x * blockDim.x) {
        int row = idx >> 6;
        int dv = idx & 63;
        int k = inds[row];
        float4 xv = ((const float4*)lat)[idx];
        float4 qv = ((const float4*)(emb + (size_t)k * DIM))[dv];
        float d0 = qv.x - xv.x, d1 = qv.y - xv.y, d2 = qv.z - xv.z, d3 = qv.w - xv.w;
        float4 o;
        o.x = xv.x + d0; o.y = xv.y + d1; o.z = xv.z + d2; o.w = xv.w + d3;
        ((float4*)out)[idx] = o;
        acc += (double)d0 * d0 + (double)d1 * d1 + (double)d2 * d2 + (double)d3 * d3;
    }
    #pragma unroll
    for (int off = 32; off >= 1; off >>= 1) acc += __shfl_xor(acc, off);
    if ((tid & 63) == 0) wsum[tid >> 6] = acc;
    __syncthreads();
    if (tid == 0) partials[blockIdx.x] = wsum[0] + wsum[1] + wsum[2] + wsum[3];
}

// ---------------- finalize ----------------
__global__ __launch_bounds__(256) void finalize_kernel(const int* __restrict__ hist,
                                                       const double* __restrict__ partials,
                                                       float* __restrict__ out_tail) {
    __shared__ double sh[256];
    const int tid = threadIdx.x;
    double s = 0.0;
    for (int i = tid; i < 2048; i += 256) s += partials[i];
    sh[tid] = s; __syncthreads();
    for (int st = 128; st > 0; st >>= 1) {
        if (tid < st) sh[tid] += sh[tid + st];
        __syncthreads();
    }
    double sumsq = sh[0];
    __syncthreads();
    double e = 0.0;
    for (int k = tid; k < KC; k += 256) {
        double p = (double)hist[k] / (double)N_ROWS;
        e += p * log(p + 1e-10);
    }
    sh[tid] = e; __syncthreads();
    for (int st = 128; st > 0; st >>= 1) {
        if (tid < st) sh[tid] += sh[tid + st];
        __syncthreads();
    }
    if (tid == 0) {
        double mse = sumsq / (double)((size_t)N_ROWS * DIM);
        out_tail[0] = (float)(1.25 * mse);
        out_tail[1] = (float)exp(-sh[0]);
    }
}

extern "C" void kernel_launch(void* const* d_in, const int* in_sizes, int n_in,
                              void* d_out, int out_size, void* d_ws, size_t ws_size,
                              hipStream_t stream) {
    const float* lat = (const float*)d_in[0];
    const float* emb = (const float*)d_in[1];
    float* out = (float*)d_out;

    char* ws = (char*)d_ws;
    int*    hist     = (int*)(ws);                    // 4 KB
    float*  enorm    = (float*)(ws + 4096);           // 4 KB
    int*    inds     = (int*)(ws + 8192);             // 128 KB
    double* partials = (double*)(ws + 139264);        // 16 KB
    float*  resv     = (float*)(ws + 155648);         // 1 MB
    int*    resi     = (int*)(ws + 155648 + 1048576); // 1 MB
    u16*    eh       = (u16*)(ws + 155648 + 2097152); // 512 KB
    u16*    el       = (u16*)(ws + 155648 + 2621440); // 512 KB
    const size_t WS_NEED = 155648 + 3145728;

    hipMemsetAsync(hist, 0, KC * sizeof(int), stream);
    enorm_kernel<<<KC / 256, 256, 0, stream>>>(emb, enorm);

    if (ws_size >= WS_NEED) {
        // d_out doubles as scratch for split-x until gather overwrites it
        u16* xh = (u16*)out;
        u16* xl = xh + (size_t)N_ROWS * DIM;
        split_kernel<<<1024, 256, 0, stream>>>(lat, xh, xl, N_ROWS * DIM / 4);
        split_kernel<<<64, 256, 0, stream>>>(emb, eh, el, KC * DIM / 4);
        dim3 grid(N_ROWS / 128, KC / 128);
        mfma_argmin_kernel<<<grid, 256, 0, stream>>>(xh, xl, eh, el, enorm, resv, resi);
        combine_kernel<<<N_ROWS / 256, 256, 0, stream>>>(resv, resi, inds);
    } else {
        argmin_kernel<<<N_ROWS / BM, 256, 0, stream>>>(lat, emb, enorm, inds);
    }
    hist_kernel<<<N_ROWS / 256, 256, 0, stream>>>(inds, hist);
    gather_kernel<<<2048, 256, 0, stream>>>(lat, emb, inds, out, partials);
    finalize_kernel<<<1, 256, 0, stream>>>(hist, partials, out + (size_t)N_ROWS * DIM);
}

// Round 5
// 99.347 us; speedup vs baseline: 18.2509x; 1.2887x over previous
//
#include <hip/hip_runtime.h>
#include <math.h>

#define N_ROWS 32768
#define DIM    256
#define KC     1024
#define BM     64
#define BN     64
#define DSTEP  32
#define PAD_M  68

typedef unsigned short u16;
typedef __attribute__((ext_vector_type(8))) short short8;
typedef __attribute__((ext_vector_type(4))) float f32x4;

__device__ __forceinline__ u16 bf16_rne(float f) {
    unsigned u = __float_as_uint(f);
    return (u16)((u + 0x7fffu + ((u >> 16) & 1u)) >> 16);
}

// ---------------- split latents f32 -> bf16 hi only ----------------
__global__ __launch_bounds__(256) void split_x_kernel(const float* __restrict__ in,
                                                      u16* __restrict__ hi, int n4) {
    for (int i = blockIdx.x * blockDim.x + threadIdx.x; i < n4;
         i += gridDim.x * blockDim.x) {
        float4 v = ((const float4*)in)[i];
        ushort4 hv;
        hv.x = bf16_rne(v.x); hv.y = bf16_rne(v.y);
        hv.z = bf16_rne(v.z); hv.w = bf16_rne(v.w);
        ((ushort4*)hi)[i] = hv;
    }
}

// ---------------- split codebook f32 -> bf16 hi+lo, fused row norms ----------------
// one wave per codebook row (64 lanes x float4 = 256 elements)
__global__ __launch_bounds__(256) void split_e_kernel(const float* __restrict__ emb,
                                                      u16* __restrict__ hi,
                                                      u16* __restrict__ lo,
                                                      float* __restrict__ enorm) {
    const int lane = threadIdx.x & 63;
    const int row  = blockIdx.x * 4 + (threadIdx.x >> 6);
    float4 v = ((const float4*)(emb + (size_t)row * DIM))[lane];
    float f[4] = {v.x, v.y, v.z, v.w};
    u16 hh[4], ll[4];
    float ss = 0.f;
    #pragma unroll
    for (int j = 0; j < 4; ++j) {
        hh[j] = bf16_rne(f[j]);
        float r = f[j] - __uint_as_float((unsigned)hh[j] << 16);
        ll[j] = bf16_rne(r);
        ss += f[j] * f[j];
    }
    ushort4 hv; hv.x = hh[0]; hv.y = hh[1]; hv.z = hh[2]; hv.w = hh[3];
    ushort4 lv; lv.x = ll[0]; lv.y = ll[1]; lv.z = ll[2]; lv.w = ll[3];
    ((ushort4*)(hi + (size_t)row * DIM))[lane] = hv;
    ((ushort4*)(lo + (size_t)row * DIM))[lane] = lv;
    #pragma unroll
    for (int off = 32; off >= 1; off >>= 1) ss += __shfl_xor(ss, off);
    if (lane == 0) enorm[row] = ss;
}

// ---------------- MFMA split-bf16 distance + per-colblock best ----------------
// K-extended GEMM: xh . [eh|el], 8 K-tiles of 64 (error ~2e-5 < ref's own ~3e-5 noise).
// LDS tiles [128][64] bf16, st-16B XOR swizzle realized via pre-swizzled global src.
__global__ __launch_bounds__(256) void mfma_argmin_kernel(
        const u16* __restrict__ xh,
        const u16* __restrict__ eh, const u16* __restrict__ el,
        const float* __restrict__ enorm,
        float* __restrict__ resv, int* __restrict__ resi) {
    __shared__ u16 Ablk[128 * 64];
    __shared__ u16 Bblk[128 * 64];
    __shared__ float ep_b[128][2];
    __shared__ int   ep_i[128][2];

    const int tid = threadIdx.x;
    const int l   = tid & 63;
    const int w   = tid >> 6;
    const int wr  = w >> 1, wc = w & 1;
    const size_t row0 = (size_t)blockIdx.x * 128;
    const int    col0 = blockIdx.y * 128;

    f32x4 acc[4][4];
    #pragma unroll
    for (int a = 0; a < 4; ++a)
        #pragma unroll
        for (int b = 0; b < 4; ++b)
            acc[a][b] = (f32x4){0.f, 0.f, 0.f, 0.f};

    const int srow   = l >> 3;            // row within 8-row group
    const int gchunk = (l & 7) ^ srow;    // pre-swizzled global 16B-chunk index

    for (int t = 0; t < 8; ++t) {
        const int kk0  = (t & 3) * 64;
        const u16* Bsrc = (t >> 2) ? el : eh;
        if (t) __syncthreads();
        #pragma unroll
        for (int i = 0; i < 4; ++i) {
            const int rbase = w * 32 + i * 8;
            const u16* ga = xh + (row0 + rbase + srow) * 256 + kk0 + gchunk * 8;
            __builtin_amdgcn_global_load_lds(
                (const __attribute__((address_space(1))) void*)ga,
                (__attribute__((address_space(3))) void*)&Ablk[rbase * 64], 16, 0, 0);
            const u16* gb = Bsrc + (size_t)(col0 + rbase + srow) * 256 + kk0 + gchunk * 8;
            __builtin_amdgcn_global_load_lds(
                (const __attribute__((address_space(1))) void*)gb,
                (__attribute__((address_space(3))) void*)&Bblk[rbase * 64], 16, 0, 0);
        }
        __syncthreads();
        #pragma unroll
        for (int ks = 0; ks < 2; ++ks) {
            short8 af[4], bf[4];
            #pragma unroll
            for (int mf = 0; mf < 4; ++mf) {
                const int r  = wr * 64 + mf * 16 + (l & 15);
                const int ch = (ks * 4 + (l >> 4)) ^ (r & 7);
                af[mf] = *(const short8*)&Ablk[r * 64 + ch * 8];
            }
            #pragma unroll
            for (int nf = 0; nf < 4; ++nf) {
                const int r  = wc * 64 + nf * 16 + (l & 15);
                const int ch = (ks * 4 + (l >> 4)) ^ (r & 7);
                bf[nf] = *(const short8*)&Bblk[r * 64 + ch * 8];
            }
            #pragma unroll
            for (int mf = 0; mf < 4; ++mf)
                #pragma unroll
                for (int nf = 0; nf < 4; ++nf)
                    acc[mf][nf] = __builtin_amdgcn_mfma_f32_16x16x32_bf16(
                        af[mf], bf[nf], acc[mf][nf], 0, 0, 0);
        }
    }

    // epilogue: dist = enorm[n] - 2*dot ; per-row best within this col-block
    const int lcol  = l & 15;
    const int lrow4 = (l >> 4) * 4;
    float en[4]; int ncol[4];
    #pragma unroll
    for (int nf = 0; nf < 4; ++nf) {
        ncol[nf] = col0 + wc * 64 + nf * 16 + lcol;
        en[nf]   = enorm[ncol[nf]];
    }
    #pragma unroll
    for (int mf = 0; mf < 4; ++mf) {
        #pragma unroll
        for (int r = 0; r < 4; ++r) {
            float b = INFINITY; int bi = 0;
            #pragma unroll
            for (int nf = 0; nf < 4; ++nf) {
                float d = fmaf(-2.f, acc[mf][nf][r], en[nf]);
                if (d < b) { b = d; bi = ncol[nf]; }
            }
            #pragma unroll
            for (int m = 1; m < 16; m <<= 1) {
                float b2 = __shfl_xor(b, m);
                int   i2 = __shfl_xor(bi, m);
                if (b2 < b || (b2 == b && i2 < bi)) { b = b2; bi = i2; }
            }
            if (lcol == 0) {
                const int rr = wr * 64 + mf * 16 + lrow4 + r;
                ep_b[rr][wc] = b; ep_i[rr][wc] = bi;
            }
        }
    }
    __syncthreads();
    if (tid < 128) {
        float b = ep_b[tid][0]; int bi = ep_i[tid][0];
        float b2 = ep_b[tid][1]; int i2 = ep_i[tid][1];
        if (b2 < b || (b2 == b && i2 < bi)) { b = b2; bi = i2; }
        const size_t o = (row0 + tid) * 8 + blockIdx.y;
        resv[o] = b;
        resi[o] = bi;
    }
}

// ---------------- combine col-blocks -> inds + fused histogram ----------------
__global__ __launch_bounds__(256) void combine_kernel(const float* __restrict__ resv,
                                                      const int* __restrict__ resi,
                                                      int* __restrict__ inds,
                                                      int* __restrict__ hist) {
    const int row = blockIdx.x * 256 + threadIdx.x;
    float b = INFINITY; int bi = 0x7fffffff;
    #pragma unroll
    for (int c = 0; c < 8; ++c) {
        float v = resv[(size_t)row * 8 + c];
        int i2 = resi[(size_t)row * 8 + c];
        if (v < b || (v == b && i2 < bi)) { b = v; bi = i2; }
    }
    inds[row] = bi;
    atomicAdd(&hist[bi], 1);
}

// ---------------- fallback fp32 argmin (used if ws too small) ----------------
__global__ __launch_bounds__(256) void argmin_kernel(const float* __restrict__ lat,
                                                     const float* __restrict__ emb,
                                                     const float* __restrict__ enorm,
                                                     int* __restrict__ inds,
                                                     int* __restrict__ hist) {
    __shared__ float As[DSTEP][PAD_M];
    __shared__ float Bs[DSTEP][PAD_M];
    __shared__ float rbest[BM][17];
    __shared__ int   ridx[BM][17];

    const int tid = threadIdx.x;
    const int tx = tid & 15;
    const int ty = tid >> 4;
    const int row0 = blockIdx.x * BM;
    const int lm  = tid >> 2;
    const int ld0 = (tid & 3) * 8;

    float best[4];
    int bidx[4];
    #pragma unroll
    for (int i = 0; i < 4; ++i) { best[i] = INFINITY; bidx[i] = 0; }

    for (int ct = 0; ct < KC / BN; ++ct) {
        float acc[4][4];
        #pragma unroll
        for (int i = 0; i < 4; ++i)
            #pragma unroll
            for (int j = 0; j < 4; ++j) acc[i][j] = 0.f;

        for (int dc = 0; dc < DIM; dc += DSTEP) {
            const float* ap = lat + (size_t)(row0 + lm) * DIM + dc + ld0;
            float4 a0 = *(const float4*)ap;
            float4 a1 = *(const float4*)(ap + 4);
            As[ld0 + 0][lm] = a0.x; As[ld0 + 1][lm] = a0.y;
            As[ld0 + 2][lm] = a0.z; As[ld0 + 3][lm] = a0.w;
            As[ld0 + 4][lm] = a1.x; As[ld0 + 5][lm] = a1.y;
            As[ld0 + 6][lm] = a1.z; As[ld0 + 7][lm] = a1.w;
            const float* bp = emb + (size_t)(ct * BN + lm) * DIM + dc + ld0;
            float4 b0 = *(const float4*)bp;
            float4 b1 = *(const float4*)(bp + 4);
            Bs[ld0 + 0][lm] = b0.x; Bs[ld0 + 1][lm] = b0.y;
            Bs[ld0 + 2][lm] = b0.z; Bs[ld0 + 3][lm] = b0.w;
            Bs[ld0 + 4][lm] = b1.x; Bs[ld0 + 5][lm] = b1.y;
            Bs[ld0 + 6][lm] = b1.z; Bs[ld0 + 7][lm] = b1.w;
            __syncthreads();
            #pragma unroll
            for (int d = 0; d < DSTEP; ++d) {
                float4 av = *(const float4*)&As[d][ty * 4];
                float4 bv = *(const float4*)&Bs[d][tx * 4];
                float a[4] = {av.x, av.y, av.z, av.w};
                float b[4] = {bv.x, bv.y, bv.z, bv.w};
                #pragma unroll
                for (int i = 0; i < 4; ++i)
                    #pragma unroll
                    for (int j = 0; j < 4; ++j)
                        acc[i][j] = fmaf(a[i], b[j], acc[i][j]);
            }
            __syncthreads();
        }
        #pragma unroll
        for (int j = 0; j < 4; ++j) {
            int n = ct * BN + tx * 4 + j;
            float en = enorm[n];
            #pragma unroll
            for (int i = 0; i < 4; ++i) {
                float dist = fmaf(-2.f, acc[i][j], en);
                if (dist < best[i]) { best[i] = dist; bidx[i] = n; }
            }
        }
    }
    #pragma unroll
    for (int i = 0; i < 4; ++i) {
        rbest[ty * 4 + i][tx] = best[i];
        ridx [ty * 4 + i][tx] = bidx[i];
    }
    __syncthreads();
    if (tid < BM) {
        float g1 = INFINITY;
        int i1 = 0x7fffffff;
        for (int t = 0; t < 16; ++t) {
            float d = rbest[tid][t];
            int   ix = ridx[tid][t];
            if (d < g1 || (d == g1 && ix < i1)) { g1 = d; i1 = ix; }
        }
        inds[row0 + tid] = i1;
        atomicAdd(&hist[i1], 1);
    }
}

// ---------------- fallback enorm (ws-small path) ----------------
__global__ __launch_bounds__(256) void enorm_kernel(const float* __restrict__ emb,
                                                    float* __restrict__ enorm) {
    int k = blockIdx.x * blockDim.x + threadIdx.x;
    if (k >= KC) return;
    const float4* row = (const float4*)(emb + (size_t)k * DIM);
    float s = 0.f;
    #pragma unroll 4
    for (int i = 0; i < DIM / 4; ++i) {
        float4 v = row[i];
        s += v.x * v.x + v.y * v.y + v.z * v.z + v.w * v.w;
    }
    enorm[k] = s;
}

// ---------------- gather + quantized_st + MSE partials ----------------
__global__ __launch_bounds__(256) void gather_kernel(const float* __restrict__ lat,
                                                     const float* __restrict__ emb,
                                                     const int* __restrict__ inds,
                                                     float* __restrict__ out,
                                                     double* __restrict__ partials) {
    __shared__ double wsum[4];
    const int tid = threadIdx.x;
    double acc = 0.0;
    const int nvec = N_ROWS * DIM / 4;
    for (int idx = blockIdx.x * blockDim.x + tid; idx < nvec; idx += gridDim.x * blockDim.x) {
        int row = idx >> 6;
        int dv = idx & 63;
        int k = inds[row];
        float4 xv = ((const float4*)lat)[idx];
        float4 qv = ((const float4*)(emb + (size_t)k * DIM))[dv];
        float d0 = qv.x - xv.x, d1 = qv.y - xv.y, d2 = qv.z - xv.z, d3 = qv.w - xv.w;
        float4 o;
        o.x = xv.x + d0; o.y = xv.y + d1; o.z = xv.z + d2; o.w = xv.w + d3;
        ((float4*)out)[idx] = o;
        acc += (double)d0 * d0 + (double)d1 * d1 + (double)d2 * d2 + (double)d3 * d3;
    }
    #pragma unroll
    for (int off = 32; off >= 1; off >>= 1) acc += __shfl_xor(acc, off);
    if ((tid & 63) == 0) wsum[tid >> 6] = acc;
    __syncthreads();
    if (tid == 0) partials[blockIdx.x] = wsum[0] + wsum[1] + wsum[2] + wsum[3];
}

// ---------------- finalize ----------------
__global__ __launch_bounds__(256) void finalize_kernel(const int* __restrict__ hist,
                                                       const double* __restrict__ partials,
                                                       float* __restrict__ out_tail) {
    __shared__ double sh[256];
    const int tid = threadIdx.x;
    double s = 0.0;
    for (int i = tid; i < 2048; i += 256) s += partials[i];
    sh[tid] = s; __syncthreads();
    for (int st = 128; st > 0; st >>= 1) {
        if (tid < st) sh[tid] += sh[tid + st];
        __syncthreads();
    }
    double sumsq = sh[0];
    __syncthreads();
    double e = 0.0;
    for (int k = tid; k < KC; k += 256) {
        double p = (double)hist[k] / (double)N_ROWS;
        e += p * log(p + 1e-10);
    }
    sh[tid] = e; __syncthreads();
    for (int st = 128; st > 0; st >>= 1) {
        if (tid < st) sh[tid] += sh[tid + st];
        __syncthreads();
    }
    if (tid == 0) {
        double mse = sumsq / (double)((size_t)N_ROWS * DIM);
        out_tail[0] = (float)(1.25 * mse);
        out_tail[1] = (float)exp(-sh[0]);
    }
}

extern "C" void kernel_launch(void* const* d_in, const int* in_sizes, int n_in,
                              void* d_out, int out_size, void* d_ws, size_t ws_size,
                              hipStream_t stream) {
    const float* lat = (const float*)d_in[0];
    const float* emb = (const float*)d_in[1];
    float* out = (float*)d_out;

    char* ws = (char*)d_ws;
    int*    hist     = (int*)(ws);                    // 4 KB
    float*  enorm    = (float*)(ws + 4096);           // 4 KB
    int*    inds     = (int*)(ws + 8192);             // 128 KB
    double* partials = (double*)(ws + 139264);        // 16 KB
    float*  resv     = (float*)(ws + 155648);         // 1 MB
    int*    resi     = (int*)(ws + 155648 + 1048576); // 1 MB
    u16*    eh       = (u16*)(ws + 155648 + 2097152); // 512 KB
    u16*    el       = (u16*)(ws + 155648 + 2621440); // 512 KB
    const size_t WS_NEED = 155648 + 3145728;

    hipMemsetAsync(hist, 0, KC * sizeof(int), stream);

    if (ws_size >= WS_NEED) {
        // d_out doubles as scratch for xh until gather overwrites it (16 MB < 32 MB)
        u16* xh = (u16*)out;
        split_x_kernel<<<1024, 256, 0, stream>>>(lat, xh, N_ROWS * DIM / 4);
        split_e_kernel<<<KC / 4, 256, 0, stream>>>(emb, eh, el, enorm);
        dim3 grid(N_ROWS / 128, KC / 128);
        mfma_argmin_kernel<<<grid, 256, 0, stream>>>(xh, eh, el, enorm, resv, resi);
        combine_kernel<<<N_ROWS / 256, 256, 0, stream>>>(resv, resi, inds, hist);
    } else {
        enorm_kernel<<<KC / 256, 256, 0, stream>>>(emb, enorm);
        argmin_kernel<<<N_ROWS / BM, 256, 0, stream>>>(lat, emb, enorm, inds, hist);
    }
    gather_kernel<<<2048, 256, 0, stream>>>(lat, emb, inds, out, partials);
    finalize_kernel<<<1, 256, 0, stream>>>(hist, partials, out + (size_t)N_ROWS * DIM);
}

// Round 6
// 76.144 us; speedup vs baseline: 23.8125x; 1.3047x over previous
//
#include <hip/hip_runtime.h>
#include <math.h>

#define N_ROWS 32768
#define DIM    256
#define KC     1024
#define BM     64
#define BN     64
#define DSTEP  32
#define PAD_M  68

typedef unsigned short u16;
typedef __attribute__((ext_vector_type(8))) short short8;
typedef __attribute__((ext_vector_type(4))) float f32x4;

__device__ __forceinline__ u16 bf16_rne(float f) {
    unsigned u = __float_as_uint(f);
    return (u16)((u + 0x7fffu + ((u >> 16) & 1u)) >> 16);
}

// ---------------- split codebook f32 -> bf16 hi, fused row norms ----------------
__global__ __launch_bounds__(256) void split_e_kernel(const float* __restrict__ emb,
                                                      u16* __restrict__ hi,
                                                      float* __restrict__ enorm) {
    const int lane = threadIdx.x & 63;
    const int row  = blockIdx.x * 4 + (threadIdx.x >> 6);
    float4 v = ((const float4*)(emb + (size_t)row * DIM))[lane];
    ushort4 hv;
    hv.x = bf16_rne(v.x); hv.y = bf16_rne(v.y);
    hv.z = bf16_rne(v.z); hv.w = bf16_rne(v.w);
    ((ushort4*)(hi + (size_t)row * DIM))[lane] = hv;
    float ss = v.x * v.x + v.y * v.y + v.z * v.z + v.w * v.w;
    #pragma unroll
    for (int off = 32; off >= 1; off >>= 1) ss += __shfl_xor(ss, off);
    if (lane == 0) enorm[row] = ss;
}

// ---------------- fused bf16-MFMA distance + full argmin ----------------
// Block: 128 rows x ALL 1024 cols, K=256. A staged once (f32->bf16 in-kernel,
// XOR-swizzled LDS); B (eh) double-buffered via global_load_lds w/ pre-swizzled
// source; one barrier per 64-col chunk; running argmin in registers.
__global__ __launch_bounds__(512) void fused_argmin_kernel(
        const float* __restrict__ lat, const u16* __restrict__ eh,
        const float* __restrict__ enorm,
        int* __restrict__ inds, int* __restrict__ hist) {
    __shared__ u16 Atile[128 * 256];      // 64 KB
    __shared__ u16 Bbuf[2][64 * 256];     // 2 x 32 KB
    __shared__ float ep_b[128][4];
    __shared__ int   ep_i[128][4];

    const int tid  = threadIdx.x;
    const int l    = tid & 63;
    const int w    = tid >> 6;      // 0..7
    const int wrow = w >> 2;        // 0..1 : row half
    const int wc   = w & 3;         // 0..3 : col quarter (16 cols of each chunk)
    const int lcol = l & 15;
    const int kseg = l >> 4;        // 0..3
    const size_t row0 = (size_t)blockIdx.x * 128;

    // ---- prologue: stage A, f32 -> bf16, swizzled ds_write ----
    #pragma unroll
    for (int i = 0; i < 8; ++i) {
        const int p   = i * 512 + tid;   // 0..4095 = 128 rows x 32 chunks
        const int row = p >> 5;
        const int chl = p & 31;
        const float* src = lat + (row0 + row) * 256 + chl * 8;
        float4 v0 = *(const float4*)src;
        float4 v1 = *(const float4*)(src + 4);
        short8 d;
        d[0] = (short)bf16_rne(v0.x); d[1] = (short)bf16_rne(v0.y);
        d[2] = (short)bf16_rne(v0.z); d[3] = (short)bf16_rne(v0.w);
        d[4] = (short)bf16_rne(v1.x); d[5] = (short)bf16_rne(v1.y);
        d[6] = (short)bf16_rne(v1.z); d[7] = (short)bf16_rne(v1.w);
        *(short8*)&Atile[(row * 32 + (chl ^ (row & 7))) * 8] = d;
    }
    // issue B chunk 0 (pre-swizzled global source, linear LDS dest)
    #pragma unroll
    for (int i = 0; i < 4; ++i) {
        const int p = i * 512 + tid;     // 0..2047 = 64 rows x 32 chunks
        const int row = p >> 5;
        const int chp = p & 31;
        const u16* gb = eh + (size_t)row * 256 + (chp ^ (row & 7)) * 8;
        __builtin_amdgcn_global_load_lds(
            (const __attribute__((address_space(1))) void*)gb,
            (__attribute__((address_space(3))) void*)&Bbuf[0][p * 8], 16, 0, 0);
    }
    __syncthreads();

    float best[4][4];
    int   bidx[4][4];
    #pragma unroll
    for (int mf = 0; mf < 4; ++mf)
        #pragma unroll
        for (int r = 0; r < 4; ++r) { best[mf][r] = INFINITY; bidx[mf][r] = 0; }

    for (int c = 0; c < 16; ++c) {
        if (c < 15) {   // prefetch next chunk into the other buffer
            #pragma unroll
            for (int i = 0; i < 4; ++i) {
                const int p = i * 512 + tid;
                const int row = p >> 5;
                const int chp = p & 31;
                const u16* gb = eh + (size_t)((c + 1) * 64 + row) * 256
                                   + (chp ^ (row & 7)) * 8;
                __builtin_amdgcn_global_load_lds(
                    (const __attribute__((address_space(1))) void*)gb,
                    (__attribute__((address_space(3))) void*)&Bbuf[(c + 1) & 1][p * 8],
                    16, 0, 0);
            }
        }
        const float en = enorm[c * 64 + wc * 16 + lcol];
        const u16* Bb = Bbuf[c & 1];

        f32x4 acc[4];
        #pragma unroll
        for (int mf = 0; mf < 4; ++mf) acc[mf] = (f32x4){0.f, 0.f, 0.f, 0.f};

        #pragma unroll
        for (int ks = 0; ks < 8; ++ks) {
            const int ch = ks * 4 + kseg;
            const int rb = wc * 16 + lcol;
            short8 bfr = *(const short8*)&Bb[(rb * 32 + (ch ^ (rb & 7))) * 8];
            #pragma unroll
            for (int mf = 0; mf < 4; ++mf) {
                const int ra = wrow * 64 + mf * 16 + lcol;
                short8 afr = *(const short8*)&Atile[(ra * 32 + (ch ^ (ra & 7))) * 8];
                acc[mf] = __builtin_amdgcn_mfma_f32_16x16x32_bf16(afr, bfr, acc[mf], 0, 0, 0);
            }
        }

        const int col = c * 64 + wc * 16 + lcol;
        #pragma unroll
        for (int mf = 0; mf < 4; ++mf)
            #pragma unroll
            for (int r = 0; r < 4; ++r) {
                float d = fmaf(-2.f, acc[mf][r], en);
                if (d < best[mf][r]) { best[mf][r] = d; bidx[mf][r] = col; }
            }
        __syncthreads();   // reads of Bb done; prefetched loads drained
    }

    // merge across the 16-lane col group (tie-break: smallest index)
    #pragma unroll
    for (int m = 1; m < 16; m <<= 1) {
        #pragma unroll
        for (int mf = 0; mf < 4; ++mf)
            #pragma unroll
            for (int r = 0; r < 4; ++r) {
                float b2 = __shfl_xor(best[mf][r], m);
                int   i2 = __shfl_xor(bidx[mf][r], m);
                if (b2 < best[mf][r] || (b2 == best[mf][r] && i2 < bidx[mf][r])) {
                    best[mf][r] = b2; bidx[mf][r] = i2;
                }
            }
    }
    if (lcol == 0) {
        #pragma unroll
        for (int mf = 0; mf < 4; ++mf)
            #pragma unroll
            for (int r = 0; r < 4; ++r) {
                const int row = wrow * 64 + mf * 16 + kseg * 4 + r;
                ep_b[row][wc] = best[mf][r];
                ep_i[row][wc] = bidx[mf][r];
            }
    }
    __syncthreads();
    if (tid < 128) {
        float b = ep_b[tid][0]; int bi = ep_i[tid][0];
        #pragma unroll
        for (int q = 1; q < 4; ++q) {
            float b2 = ep_b[tid][q]; int i2 = ep_i[tid][q];
            if (b2 < b || (b2 == b && i2 < bi)) { b = b2; bi = i2; }
        }
        inds[row0 + tid] = bi;
        atomicAdd(&hist[bi], 1);
    }
}

// ---------------- fallback fp32 argmin (used if ws too small) ----------------
__global__ __launch_bounds__(256) void enorm_kernel(const float* __restrict__ emb,
                                                    float* __restrict__ enorm) {
    int k = blockIdx.x * blockDim.x + threadIdx.x;
    if (k >= KC) return;
    const float4* row = (const float4*)(emb + (size_t)k * DIM);
    float s = 0.f;
    #pragma unroll 4
    for (int i = 0; i < DIM / 4; ++i) {
        float4 v = row[i];
        s += v.x * v.x + v.y * v.y + v.z * v.z + v.w * v.w;
    }
    enorm[k] = s;
}

__global__ __launch_bounds__(256) void argmin_kernel(const float* __restrict__ lat,
                                                     const float* __restrict__ emb,
                                                     const float* __restrict__ enorm,
                                                     int* __restrict__ inds,
                                                     int* __restrict__ hist) {
    __shared__ float As[DSTEP][PAD_M];
    __shared__ float Bs[DSTEP][PAD_M];
    __shared__ float rbest[BM][17];
    __shared__ int   ridx[BM][17];

    const int tid = threadIdx.x;
    const int tx = tid & 15;
    const int ty = tid >> 4;
    const int row0 = blockIdx.x * BM;
    const int lm  = tid >> 2;
    const int ld0 = (tid & 3) * 8;

    float best[4];
    int bidx[4];
    #pragma unroll
    for (int i = 0; i < 4; ++i) { best[i] = INFINITY; bidx[i] = 0; }

    for (int ct = 0; ct < KC / BN; ++ct) {
        float acc[4][4];
        #pragma unroll
        for (int i = 0; i < 4; ++i)
            #pragma unroll
            for (int j = 0; j < 4; ++j) acc[i][j] = 0.f;

        for (int dc = 0; dc < DIM; dc += DSTEP) {
            const float* ap = lat + (size_t)(row0 + lm) * DIM + dc + ld0;
            float4 a0 = *(const float4*)ap;
            float4 a1 = *(const float4*)(ap + 4);
            As[ld0 + 0][lm] = a0.x; As[ld0 + 1][lm] = a0.y;
            As[ld0 + 2][lm] = a0.z; As[ld0 + 3][lm] = a0.w;
            As[ld0 + 4][lm] = a1.x; As[ld0 + 5][lm] = a1.y;
            As[ld0 + 6][lm] = a1.z; As[ld0 + 7][lm] = a1.w;
            const float* bp = emb + (size_t)(ct * BN + lm) * DIM + dc + ld0;
            float4 b0 = *(const float4*)bp;
            float4 b1 = *(const float4*)(bp + 4);
            Bs[ld0 + 0][lm] = b0.x; Bs[ld0 + 1][lm] = b0.y;
            Bs[ld0 + 2][lm] = b0.z; Bs[ld0 + 3][lm] = b0.w;
            Bs[ld0 + 4][lm] = b1.x; Bs[ld0 + 5][lm] = b1.y;
            Bs[ld0 + 6][lm] = b1.z; Bs[ld0 + 7][lm] = b1.w;
            __syncthreads();
            #pragma unroll
            for (int d = 0; d < DSTEP; ++d) {
                float4 av = *(const float4*)&As[d][ty * 4];
                float4 bv = *(const float4*)&Bs[d][tx * 4];
                float a[4] = {av.x, av.y, av.z, av.w};
                float b[4] = {bv.x, bv.y, bv.z, bv.w};
                #pragma unroll
                for (int i = 0; i < 4; ++i)
                    #pragma unroll
                    for (int j = 0; j < 4; ++j)
                        acc[i][j] = fmaf(a[i], b[j], acc[i][j]);
            }
            __syncthreads();
        }
        #pragma unroll
        for (int j = 0; j < 4; ++j) {
            int n = ct * BN + tx * 4 + j;
            float en = enorm[n];
            #pragma unroll
            for (int i = 0; i < 4; ++i) {
                float dist = fmaf(-2.f, acc[i][j], en);
                if (dist < best[i]) { best[i] = dist; bidx[i] = n; }
            }
        }
    }
    #pragma unroll
    for (int i = 0; i < 4; ++i) {
        rbest[ty * 4 + i][tx] = best[i];
        ridx [ty * 4 + i][tx] = bidx[i];
    }
    __syncthreads();
    if (tid < BM) {
        float g1 = INFINITY;
        int i1 = 0x7fffffff;
        for (int t = 0; t < 16; ++t) {
            float d = rbest[tid][t];
            int   ix = ridx[tid][t];
            if (d < g1 || (d == g1 && ix < i1)) { g1 = d; i1 = ix; }
        }
        inds[row0 + tid] = i1;
        atomicAdd(&hist[i1], 1);
    }
}

// ---------------- gather + quantized_st + MSE partials ----------------
__global__ __launch_bounds__(256) void gather_kernel(const float* __restrict__ lat,
                                                     const float* __restrict__ emb,
                                                     const int* __restrict__ inds,
                                                     float* __restrict__ out,
                                                     double* __restrict__ partials) {
    __shared__ double wsum[4];
    const int tid = threadIdx.x;
    double acc = 0.0;
    const int nvec = N_ROWS * DIM / 4;
    for (int idx = blockIdx.x * blockDim.x + tid; idx < nvec; idx += gridDim.x * blockDim.x) {
        int row = idx >> 6;
        int dv = idx & 63;
        int k = inds[row];
        float4 xv = ((const float4*)lat)[idx];
        float4 qv = ((const float4*)(emb + (size_t)k * DIM))[dv];
        float d0 = qv.x - xv.x, d1 = qv.y - xv.y, d2 = qv.z - xv.z, d3 = qv.w - xv.w;
        float4 o;
        o.x = xv.x + d0; o.y = xv.y + d1; o.z = xv.z + d2; o.w = xv.w + d3;
        ((float4*)out)[idx] = o;
        acc += (double)d0 * d0 + (double)d1 * d1 + (double)d2 * d2 + (double)d3 * d3;
    }
    #pragma unroll
    for (int off = 32; off >= 1; off >>= 1) acc += __shfl_xor(acc, off);
    if ((tid & 63) == 0) wsum[tid >> 6] = acc;
    __syncthreads();
    if (tid == 0) partials[blockIdx.x] = wsum[0] + wsum[1] + wsum[2] + wsum[3];
}

// ---------------- finalize ----------------
__global__ __launch_bounds__(256) void finalize_kernel(const int* __restrict__ hist,
                                                       const double* __restrict__ partials,
                                                       float* __restrict__ out_tail) {
    __shared__ double sh[256];
    const int tid = threadIdx.x;
    double s = 0.0;
    for (int i = tid; i < 2048; i += 256) s += partials[i];
    sh[tid] = s; __syncthreads();
    for (int st = 128; st > 0; st >>= 1) {
        if (tid < st) sh[tid] += sh[tid + st];
        __syncthreads();
    }
    double sumsq = sh[0];
    __syncthreads();
    double e = 0.0;
    for (int k = tid; k < KC; k += 256) {
        double p = (double)hist[k] / (double)N_ROWS;
        e += p * log(p + 1e-10);
    }
    sh[tid] = e; __syncthreads();
    for (int st = 128; st > 0; st >>= 1) {
        if (tid < st) sh[tid] += sh[tid + st];
        __syncthreads();
    }
    if (tid == 0) {
        double mse = sumsq / (double)((size_t)N_ROWS * DIM);
        out_tail[0] = (float)(1.25 * mse);
        out_tail[1] = (float)exp(-sh[0]);
    }
}

extern "C" void kernel_launch(void* const* d_in, const int* in_sizes, int n_in,
                              void* d_out, int out_size, void* d_ws, size_t ws_size,
                              hipStream_t stream) {
    const float* lat = (const float*)d_in[0];
    const float* emb = (const float*)d_in[1];
    float* out = (float*)d_out;

    char* ws = (char*)d_ws;
    int*    hist     = (int*)(ws);                    // 4 KB
    float*  enorm    = (float*)(ws + 4096);           // 4 KB
    int*    inds     = (int*)(ws + 8192);             // 128 KB
    double* partials = (double*)(ws + 139264);        // 16 KB
    u16*    eh       = (u16*)(ws + 155648);           // 512 KB
    const size_t WS_NEED = 155648 + 524288;

    hipMemsetAsync(hist, 0, KC * sizeof(int), stream);

    if (ws_size >= WS_NEED) {
        split_e_kernel<<<KC / 4, 256, 0, stream>>>(emb, eh, enorm);
        fused_argmin_kernel<<<N_ROWS / 128, 512, 0, stream>>>(lat, eh, enorm, inds, hist);
    } else {
        enorm_kernel<<<KC / 256, 256, 0, stream>>>(emb, enorm);
        argmin_kernel<<<N_ROWS / BM, 256, 0, stream>>>(lat, emb, enorm, inds, hist);
    }
    gather_kernel<<<2048, 256, 0, stream>>>(lat, emb, inds, out, partials);
    finalize_kernel<<<1, 256, 0, stream>>>(hist, partials, out + (size_t)N_ROWS * DIM);
}

// Round 8
// 61.538 us; speedup vs baseline: 29.4643x; 1.2373x over previous
//
#include <hip/hip_runtime.h>
#include <math.h>

#define N_ROWS 32768
#define DIM    256
#define KC     1024
#define BM     64
#define BN     64
#define DSTEP  32
#define PAD_M  68

typedef unsigned short u16;
typedef __attribute__((ext_vector_type(8))) short short8;
typedef __attribute__((ext_vector_type(4))) float f32x4;

__device__ __forceinline__ u16 bf16_rne(float f) {
    unsigned u = __float_as_uint(f);
    return (u16)((u + 0x7fffu + ((u >> 16) & 1u)) >> 16);
}

// ---------------- split codebook f32 -> bf16, fused row norms ----------------
__global__ __launch_bounds__(256) void split_e_kernel(const float* __restrict__ emb,
                                                      u16* __restrict__ hi,
                                                      float* __restrict__ enorm) {
    const int lane = threadIdx.x & 63;
    const int row  = blockIdx.x * 4 + (threadIdx.x >> 6);
    float4 v = ((const float4*)(emb + (size_t)row * DIM))[lane];
    ushort4 hv;
    hv.x = bf16_rne(v.x); hv.y = bf16_rne(v.y);
    hv.z = bf16_rne(v.z); hv.w = bf16_rne(v.w);
    ((ushort4*)(hi + (size_t)row * DIM))[lane] = hv;
    float ss = v.x * v.x + v.y * v.y + v.z * v.z + v.w * v.w;
    #pragma unroll
    for (int off = 32; off >= 1; off >>= 1) ss += __shfl_xor(ss, off);
    if (lane == 0) enorm[row] = ss;
}

// ---------------- fused argmin (r6 structure + A-in-registers) ----------------
// Block: 512 thr / 8 waves = 2 row-halves x 4 col-quarters; 128 rows x 1024 cols.
// A staged once into swizzled LDS (f32->bf16), then hoisted into afr[4][8] regs;
// B double-buffered 64-col chunks via global_load_lds (pre-swizzled source);
// one barrier per chunk (proven r6 sync pattern). Main loop: 8 ds_read_b128 +
// 32 MFMA per wave per chunk.
__global__ __launch_bounds__(512, 2) void fused_argmin_kernel(
        const float* __restrict__ lat, const u16* __restrict__ eh,
        const float* __restrict__ enorm,
        int* __restrict__ inds, int* __restrict__ hist,
        double* __restrict__ partials) {
    __shared__ u16    Atile[128 * 256];   // 64 KB, swizzled
    __shared__ u16    Bbuf[2][64 * 256];  // 2 x 32 KB, swizzled (via src)
    __shared__ float  xn_lds[128];
    __shared__ float  ep_b[128][4];
    __shared__ int    ep_i[128][4];
    __shared__ double sred[128];

    const int tid  = threadIdx.x;
    const int l    = tid & 63;
    const int w    = tid >> 6;
    const int wrow = w >> 2;        // 0..1 : row half (64 rows)
    const int wc   = w & 3;         // 0..3 : col quarter (16 cols per 64-col chunk)
    const int lcol = l & 15;
    const int kseg = l >> 4;        // 0..3
    const size_t row0 = (size_t)blockIdx.x * 128;

    // ---- prologue: stage A (f32->bf16, swizzled) + per-row ||x||^2 ----
    #pragma unroll
    for (int i = 0; i < 8; ++i) {
        const int p   = i * 512 + tid;   // 0..4095 = 128 rows x 32 chunks
        const int row = p >> 5;
        const int chl = p & 31;
        const float* src = lat + (row0 + row) * 256 + chl * 8;
        float4 v0 = *(const float4*)src;
        float4 v1 = *(const float4*)(src + 4);
        short8 d;
        d[0] = (short)bf16_rne(v0.x); d[1] = (short)bf16_rne(v0.y);
        d[2] = (short)bf16_rne(v0.z); d[3] = (short)bf16_rne(v0.w);
        d[4] = (short)bf16_rne(v1.x); d[5] = (short)bf16_rne(v1.y);
        d[6] = (short)bf16_rne(v1.z); d[7] = (short)bf16_rne(v1.w);
        *(short8*)&Atile[(row * 32 + (chl ^ (row & 7))) * 8] = d;
        // row-norm: 32 consecutive threads (one 32-lane group) share a row
        float ss = v0.x * v0.x + v0.y * v0.y + v0.z * v0.z + v0.w * v0.w
                 + v1.x * v1.x + v1.y * v1.y + v1.z * v1.z + v1.w * v1.w;
        ss += __shfl_xor(ss, 1);  ss += __shfl_xor(ss, 2);
        ss += __shfl_xor(ss, 4);  ss += __shfl_xor(ss, 8);
        ss += __shfl_xor(ss, 16);
        if ((tid & 31) == 0) xn_lds[row] = ss;   // unique writer per row
    }
    // issue B chunk 0 (pre-swizzled global source, linear LDS dest)
    #pragma unroll
    for (int i = 0; i < 4; ++i) {
        const int p = i * 512 + tid;     // 0..2047 = 64 rows x 32 chunks
        const int row = p >> 5;
        const int chp = p & 31;
        const u16* gb = eh + (size_t)row * 256 + (chp ^ (row & 7)) * 8;
        __builtin_amdgcn_global_load_lds(
            (const __attribute__((address_space(1))) void*)gb,
            (__attribute__((address_space(3))) void*)&Bbuf[0][p * 8], 16, 0, 0);
    }
    __syncthreads();

    // ---- hoist A fragments into registers (read LDS once) ----
    short8 afr[4][8];
    #pragma unroll
    for (int mf = 0; mf < 4; ++mf) {
        const int ra = wrow * 64 + mf * 16 + lcol;
        #pragma unroll
        for (int ks = 0; ks < 8; ++ks) {
            const int ch = ks * 4 + kseg;
            afr[mf][ks] = *(const short8*)&Atile[(ra * 32 + (ch ^ (ra & 7))) * 8];
        }
    }

    float best[4][4];
    int   bidx[4][4];
    #pragma unroll
    for (int mf = 0; mf < 4; ++mf)
        #pragma unroll
        for (int r = 0; r < 4; ++r) { best[mf][r] = INFINITY; bidx[mf][r] = 0; }

    const int rb = wc * 16 + lcol;
    for (int c = 0; c < 16; ++c) {
        if (c < 15) {   // prefetch next chunk into the other buffer
            #pragma unroll
            for (int i = 0; i < 4; ++i) {
                const int p = i * 512 + tid;
                const int row = p >> 5;
                const int chp = p & 31;
                const u16* gb = eh + (size_t)((c + 1) * 64 + row) * 256
                                   + (chp ^ (row & 7)) * 8;
                __builtin_amdgcn_global_load_lds(
                    (const __attribute__((address_space(1))) void*)gb,
                    (__attribute__((address_space(3))) void*)&Bbuf[(c + 1) & 1][p * 8],
                    16, 0, 0);
            }
        }
        const u16* Bb = Bbuf[c & 1];
        const float en = enorm[c * 64 + rb];

        short8 bq[8];
        #pragma unroll
        for (int ks = 0; ks < 8; ++ks) {
            const int ch = ks * 4 + kseg;
            bq[ks] = *(const short8*)&Bb[(rb * 32 + (ch ^ (rb & 7))) * 8];
        }

        f32x4 acc[4];
        #pragma unroll
        for (int mf = 0; mf < 4; ++mf) acc[mf] = (f32x4){0.f, 0.f, 0.f, 0.f};
        #pragma unroll
        for (int ks = 0; ks < 8; ++ks)
            #pragma unroll
            for (int mf = 0; mf < 4; ++mf)
                acc[mf] = __builtin_amdgcn_mfma_f32_16x16x32_bf16(
                    afr[mf][ks], bq[ks], acc[mf], 0, 0, 0);

        const int col = c * 64 + rb;
        #pragma unroll
        for (int mf = 0; mf < 4; ++mf)
            #pragma unroll
            for (int r = 0; r < 4; ++r) {
                float d = fmaf(-2.f, acc[mf][r], en);
                if (d < best[mf][r]) { best[mf][r] = d; bidx[mf][r] = col; }
            }
        __syncthreads();   // Bb reads done; prefetched loads drained
    }

    // merge across the 16-lane col group (tie-break: smallest index)
    #pragma unroll
    for (int m = 1; m < 16; m <<= 1) {
        #pragma unroll
        for (int mf = 0; mf < 4; ++mf)
            #pragma unroll
            for (int r = 0; r < 4; ++r) {
                float b2 = __shfl_xor(best[mf][r], m);
                int   i2 = __shfl_xor(bidx[mf][r], m);
                if (b2 < best[mf][r] || (b2 == best[mf][r] && i2 < bidx[mf][r])) {
                    best[mf][r] = b2; bidx[mf][r] = i2;
                }
            }
    }
    if (lcol == 0) {
        #pragma unroll
        for (int mf = 0; mf < 4; ++mf)
            #pragma unroll
            for (int r = 0; r < 4; ++r) {
                const int rr = wrow * 64 + mf * 16 + kseg * 4 + r;
                ep_b[rr][wc] = best[mf][r];
                ep_i[rr][wc] = bidx[mf][r];
            }
    }
    __syncthreads();

    // final per-row merge; dist = ||x||^2 + best(enorm - 2 dot)
    if (tid < 128) {
        float b = ep_b[tid][0]; int bi = ep_i[tid][0];
        #pragma unroll
        for (int q = 1; q < 4; ++q) {
            float b2 = ep_b[tid][q]; int i2 = ep_i[tid][q];
            if (b2 < b || (b2 == b && i2 < bi)) { b = b2; bi = i2; }
        }
        inds[row0 + tid] = bi;
        atomicAdd(&hist[bi], 1);
        sred[tid] = (double)xn_lds[tid] + (double)b;
    }
    __syncthreads();
    for (int st = 64; st >= 1; st >>= 1) {
        if (tid < st) sred[tid] += sred[tid + st];
        __syncthreads();
    }
    if (tid == 0) partials[blockIdx.x] = sred[0];
}

// ---------------- write quantized output ----------------
__global__ __launch_bounds__(256) void writeq_kernel(const float* __restrict__ emb,
                                                     const int* __restrict__ inds,
                                                     float* __restrict__ out) {
    const int nvec = N_ROWS * DIM / 4;
    for (int idx = blockIdx.x * 256 + threadIdx.x; idx < nvec;
         idx += gridDim.x * 256) {
        int row = idx >> 6;
        int dv  = idx & 63;
        int k   = inds[row];
        ((float4*)out)[idx] = ((const float4*)(emb + (size_t)k * DIM))[dv];
    }
}

// ---------------- finalize: vq_loss + perplexity ----------------
__global__ __launch_bounds__(256) void finalize_kernel(const int* __restrict__ hist,
                                                       const double* __restrict__ partials,
                                                       int np,
                                                       float* __restrict__ out_tail) {
    __shared__ double sh[256];
    const int tid = threadIdx.x;
    double s = 0.0;
    for (int i = tid; i < np; i += 256) s += partials[i];
    sh[tid] = s; __syncthreads();
    for (int st = 128; st > 0; st >>= 1) {
        if (tid < st) sh[tid] += sh[tid + st];
        __syncthreads();
    }
    double sumsq = sh[0];
    __syncthreads();
    double e = 0.0;
    for (int k = tid; k < KC; k += 256) {
        double p = (double)hist[k] / (double)N_ROWS;
        e += p * log(p + 1e-10);
    }
    sh[tid] = e; __syncthreads();
    for (int st = 128; st > 0; st >>= 1) {
        if (tid < st) sh[tid] += sh[tid + st];
        __syncthreads();
    }
    if (tid == 0) {
        double mse = sumsq / (double)((size_t)N_ROWS * DIM);
        out_tail[0] = (float)(1.25 * mse);
        out_tail[1] = (float)exp(-sh[0]);
    }
}

// ================= fallback path (ws too small) =================
__global__ __launch_bounds__(256) void enorm_kernel(const float* __restrict__ emb,
                                                    float* __restrict__ enorm) {
    int k = blockIdx.x * blockDim.x + threadIdx.x;
    if (k >= KC) return;
    const float4* row = (const float4*)(emb + (size_t)k * DIM);
    float s = 0.f;
    #pragma unroll 4
    for (int i = 0; i < DIM / 4; ++i) {
        float4 v = row[i];
        s += v.x * v.x + v.y * v.y + v.z * v.z + v.w * v.w;
    }
    enorm[k] = s;
}

__global__ __launch_bounds__(256) void argmin_kernel(const float* __restrict__ lat,
                                                     const float* __restrict__ emb,
                                                     const float* __restrict__ enorm,
                                                     int* __restrict__ inds,
                                                     int* __restrict__ hist) {
    __shared__ float As[DSTEP][PAD_M];
    __shared__ float Bs[DSTEP][PAD_M];
    __shared__ float rbest[BM][17];
    __shared__ int   ridx[BM][17];

    const int tid = threadIdx.x;
    const int tx = tid & 15;
    const int ty = tid >> 4;
    const int row0 = blockIdx.x * BM;
    const int lm  = tid >> 2;
    const int ld0 = (tid & 3) * 8;

    float best[4];
    int bidx[4];
    #pragma unroll
    for (int i = 0; i < 4; ++i) { best[i] = INFINITY; bidx[i] = 0; }

    for (int ct = 0; ct < KC / BN; ++ct) {
        float acc[4][4];
        #pragma unroll
        for (int i = 0; i < 4; ++i)
            #pragma unroll
            for (int j = 0; j < 4; ++j) acc[i][j] = 0.f;

        for (int dc = 0; dc < DIM; dc += DSTEP) {
            const float* ap = lat + (size_t)(row0 + lm) * DIM + dc + ld0;
            float4 a0 = *(const float4*)ap;
            float4 a1 = *(const float4*)(ap + 4);
            As[ld0 + 0][lm] = a0.x; As[ld0 + 1][lm] = a0.y;
            As[ld0 + 2][lm] = a0.z; As[ld0 + 3][lm] = a0.w;
            As[ld0 + 4][lm] = a1.x; As[ld0 + 5][lm] = a1.y;
            As[ld0 + 6][lm] = a1.z; As[ld0 + 7][lm] = a1.w;
            const float* bp = emb + (size_t)(ct * BN + lm) * DIM + dc + ld0;
            float4 b0 = *(const float4*)bp;
            float4 b1 = *(const float4*)(bp + 4);
            Bs[ld0 + 0][lm] = b0.x; Bs[ld0 + 1][lm] = b0.y;
            Bs[ld0 + 2][lm] = b0.z; Bs[ld0 + 3][lm] = b0.w;
            Bs[ld0 + 4][lm] = b1.x; Bs[ld0 + 5][lm] = b1.y;
            Bs[ld0 + 6][lm] = b1.z; Bs[ld0 + 7][lm] = b1.w;
            __syncthreads();
            #pragma unroll
            for (int d = 0; d < DSTEP; ++d) {
                float4 av = *(const float4*)&As[d][ty * 4];
                float4 bv = *(const float4*)&Bs[d][tx * 4];
                float a[4] = {av.x, av.y, av.z, av.w};
                float b[4] = {bv.x, bv.y, bv.z, bv.w};
                #pragma unroll
                for (int i = 0; i < 4; ++i)
                    #pragma unroll
                    for (int j = 0; j < 4; ++j)
                        acc[i][j] = fmaf(a[i], b[j], acc[i][j]);
            }
            __syncthreads();
        }
        #pragma unroll
        for (int j = 0; j < 4; ++j) {
            int n = ct * BN + tx * 4 + j;
            float en = enorm[n];
            #pragma unroll
            for (int i = 0; i < 4; ++i) {
                float dist = fmaf(-2.f, acc[i][j], en);
                if (dist < best[i]) { best[i] = dist; bidx[i] = n; }
            }
        }
    }
    #pragma unroll
    for (int i = 0; i < 4; ++i) {
        rbest[ty * 4 + i][tx] = best[i];
        ridx [ty * 4 + i][tx] = bidx[i];
    }
    __syncthreads();
    if (tid < BM) {
        float g1 = INFINITY;
        int i1 = 0x7fffffff;
        for (int t = 0; t < 16; ++t) {
            float d = rbest[tid][t];
            int   ix = ridx[tid][t];
            if (d < g1 || (d == g1 && ix < i1)) { g1 = d; i1 = ix; }
        }
        inds[row0 + tid] = i1;
        atomicAdd(&hist[i1], 1);
    }
}

__global__ __launch_bounds__(256) void gather_kernel(const float* __restrict__ lat,
                                                     const float* __restrict__ emb,
                                                     const int* __restrict__ inds,
                                                     float* __restrict__ out,
                                                     double* __restrict__ partials) {
    __shared__ double wsum[4];
    const int tid = threadIdx.x;
    double acc = 0.0;
    const int nvec = N_ROWS * DIM / 4;
    for (int idx = blockIdx.x * blockDim.x + tid; idx < nvec; idx += gridDim.x * blockDim.x) {
        int row = idx >> 6;
        int dv = idx & 63;
        int k = inds[row];
        float4 xv = ((const float4*)lat)[idx];
        float4 qv = ((const float4*)(emb + (size_t)k * DIM))[dv];
        float d0 = qv.x - xv.x, d1 = qv.y - xv.y, d2 = qv.z - xv.z, d3 = qv.w - xv.w;
        float4 o;
        o.x = xv.x + d0; o.y = xv.y + d1; o.z = xv.z + d2; o.w = xv.w + d3;
        ((float4*)out)[idx] = o;
        acc += (double)d0 * d0 + (double)d1 * d1 + (double)d2 * d2 + (double)d3 * d3;
    }
    #pragma unroll
    for (int off = 32; off >= 1; off >>= 1) acc += __shfl_xor(acc, off);
    if ((tid & 63) == 0) wsum[tid >> 6] = acc;
    __syncthreads();
    if (tid == 0) partials[blockIdx.x] = wsum[0] + wsum[1] + wsum[2] + wsum[3];
}

extern "C" void kernel_launch(void* const* d_in, const int* in_sizes, int n_in,
                              void* d_out, int out_size, void* d_ws, size_t ws_size,
                              hipStream_t stream) {
    const float* lat = (const float*)d_in[0];
    const float* emb = (const float*)d_in[1];
    float* out = (float*)d_out;

    char* ws = (char*)d_ws;
    int*    hist     = (int*)(ws);                    // 4 KB
    float*  enorm    = (float*)(ws + 4096);           // 4 KB
    int*    inds     = (int*)(ws + 8192);             // 128 KB
    double* partials = (double*)(ws + 139264);        // 16 KB
    u16*    eh       = (u16*)(ws + 155648);           // 512 KB
    const size_t WS_NEED = 155648 + 524288;

    hipMemsetAsync(hist, 0, KC * sizeof(int), stream);

    if (ws_size >= WS_NEED) {
        split_e_kernel<<<KC / 4, 256, 0, stream>>>(emb, eh, enorm);
        fused_argmin_kernel<<<N_ROWS / 128, 512, 0, stream>>>(lat, eh, enorm,
                                                              inds, hist, partials);
        writeq_kernel<<<2048, 256, 0, stream>>>(emb, inds, out);
        finalize_kernel<<<1, 256, 0, stream>>>(hist, partials, N_ROWS / 128,
                                               out + (size_t)N_ROWS * DIM);
    } else {
        enorm_kernel<<<KC / 256, 256, 0, stream>>>(emb, enorm);
        argmin_kernel<<<N_ROWS / BM, 256, 0, stream>>>(lat, emb, enorm, inds, hist);
        gather_kernel<<<2048, 256, 0, stream>>>(lat, emb, inds, out, partials);
        finalize_kernel<<<1, 256, 0, stream>>>(hist, partials, 2048,
                                               out + (size_t)N_ROWS * DIM);
    }
}

// Round 9
// 61.350 us; speedup vs baseline: 29.5545x; 1.0031x over previous
//
#include <hip/hip_runtime.h>
#include <math.h>

#define N_ROWS 32768
#define DIM    256
#define KC     1024
#define BM     64
#define BN     64
#define DSTEP  32
#define PAD_M  68

typedef unsigned short u16;
typedef __attribute__((ext_vector_type(8))) short short8;
typedef __attribute__((ext_vector_type(4))) float f32x4;

__device__ __forceinline__ u16 bf16_rne(float f) {
    unsigned u = __float_as_uint(f);
    return (u16)((u + 0x7fffu + ((u >> 16) & 1u)) >> 16);
}

// ---------------- split codebook f32 -> bf16, fused row norms ----------------
__global__ __launch_bounds__(256) void split_e_kernel(const float* __restrict__ emb,
                                                      u16* __restrict__ hi,
                                                      float* __restrict__ enorm) {
    const int lane = threadIdx.x & 63;
    const int row  = blockIdx.x * 4 + (threadIdx.x >> 6);
    float4 v = ((const float4*)(emb + (size_t)row * DIM))[lane];
    ushort4 hv;
    hv.x = bf16_rne(v.x); hv.y = bf16_rne(v.y);
    hv.z = bf16_rne(v.z); hv.w = bf16_rne(v.w);
    ((ushort4*)(hi + (size_t)row * DIM))[lane] = hv;
    float ss = v.x * v.x + v.y * v.y + v.z * v.z + v.w * v.w;
    #pragma unroll
    for (int off = 32; off >= 1; off >>= 1) ss += __shfl_xor(ss, off);
    if (lane == 0) enorm[row] = ss;
}

// ---------------- fused argmin (r8 structure, A-hoist pinned in registers) ----------
// Block: 512 thr / 8 waves = 2 row-halves x 4 col-quarters; 128 rows x 1024 cols.
// A staged once into swizzled LDS (f32->bf16), hoisted into afr[4][8] (128 VGPR).
// amdgpu_waves_per_eu(2,2) pins the RA at the 256-VGPR budget (LDS already caps
// the CU at 1 block = 2 waves/EU, so no occupancy is lost) — without it the
// backend targets 4 waves/EU and silently remats afr from LDS (r8: VGPR=112).
// B double-buffered 64-col chunks via global_load_lds (pre-swizzled source);
// one barrier per chunk. Main loop: 8 ds_read_b128 + 32 MFMA per wave per chunk.
__global__ __launch_bounds__(512)
__attribute__((amdgpu_waves_per_eu(2, 2)))
void fused_argmin_kernel(
        const float* __restrict__ lat, const u16* __restrict__ eh,
        const float* __restrict__ enorm,
        int* __restrict__ inds, int* __restrict__ hist,
        double* __restrict__ partials) {
    __shared__ u16    Atile[128 * 256];   // 64 KB, swizzled
    __shared__ u16    Bbuf[2][64 * 256];  // 2 x 32 KB, swizzled (via src)
    __shared__ float  xn_lds[128];
    __shared__ float  ep_b[128][4];
    __shared__ int    ep_i[128][4];
    __shared__ double sred[128];

    const int tid  = threadIdx.x;
    const int l    = tid & 63;
    const int w    = tid >> 6;
    const int wrow = w >> 2;        // 0..1 : row half (64 rows)
    const int wc   = w & 3;         // 0..3 : col quarter (16 cols per 64-col chunk)
    const int lcol = l & 15;
    const int kseg = l >> 4;        // 0..3
    const size_t row0 = (size_t)blockIdx.x * 128;

    // ---- prologue: stage A (f32->bf16, swizzled) + per-row ||x||^2 ----
    #pragma unroll
    for (int i = 0; i < 8; ++i) {
        const int p   = i * 512 + tid;   // 0..4095 = 128 rows x 32 chunks
        const int row = p >> 5;
        const int chl = p & 31;
        const float* src = lat + (row0 + row) * 256 + chl * 8;
        float4 v0 = *(const float4*)src;
        float4 v1 = *(const float4*)(src + 4);
        short8 d;
        d[0] = (short)bf16_rne(v0.x); d[1] = (short)bf16_rne(v0.y);
        d[2] = (short)bf16_rne(v0.z); d[3] = (short)bf16_rne(v0.w);
        d[4] = (short)bf16_rne(v1.x); d[5] = (short)bf16_rne(v1.y);
        d[6] = (short)bf16_rne(v1.z); d[7] = (short)bf16_rne(v1.w);
        *(short8*)&Atile[(row * 32 + (chl ^ (row & 7))) * 8] = d;
        // row-norm: 32 consecutive threads (one 32-lane group) share a row
        float ss = v0.x * v0.x + v0.y * v0.y + v0.z * v0.z + v0.w * v0.w
                 + v1.x * v1.x + v1.y * v1.y + v1.z * v1.z + v1.w * v1.w;
        ss += __shfl_xor(ss, 1);  ss += __shfl_xor(ss, 2);
        ss += __shfl_xor(ss, 4);  ss += __shfl_xor(ss, 8);
        ss += __shfl_xor(ss, 16);
        if ((tid & 31) == 0) xn_lds[row] = ss;   // unique writer per row
    }
    // issue B chunk 0 (pre-swizzled global source, linear LDS dest)
    #pragma unroll
    for (int i = 0; i < 4; ++i) {
        const int p = i * 512 + tid;     // 0..2047 = 64 rows x 32 chunks
        const int row = p >> 5;
        const int chp = p & 31;
        const u16* gb = eh + (size_t)row * 256 + (chp ^ (row & 7)) * 8;
        __builtin_amdgcn_global_load_lds(
            (const __attribute__((address_space(1))) void*)gb,
            (__attribute__((address_space(3))) void*)&Bbuf[0][p * 8], 16, 0, 0);
    }
    __syncthreads();

    // ---- hoist A fragments into registers (read LDS once; pinned by reg budget) ----
    short8 afr[4][8];
    #pragma unroll
    for (int mf = 0; mf < 4; ++mf) {
        const int ra = wrow * 64 + mf * 16 + lcol;
        #pragma unroll
        for (int ks = 0; ks < 8; ++ks) {
            const int ch = ks * 4 + kseg;
            afr[mf][ks] = *(const short8*)&Atile[(ra * 32 + (ch ^ (ra & 7))) * 8];
        }
    }
    __builtin_amdgcn_sched_barrier(0);   // keep the hoist hoisted

    float best[4][4];
    int   bidx[4][4];
    #pragma unroll
    for (int mf = 0; mf < 4; ++mf)
        #pragma unroll
        for (int r = 0; r < 4; ++r) { best[mf][r] = INFINITY; bidx[mf][r] = 0; }

    const int rb = wc * 16 + lcol;
    for (int c = 0; c < 16; ++c) {
        if (c < 15) {   // prefetch next chunk into the other buffer
            #pragma unroll
            for (int i = 0; i < 4; ++i) {
                const int p = i * 512 + tid;
                const int row = p >> 5;
                const int chp = p & 31;
                const u16* gb = eh + (size_t)((c + 1) * 64 + row) * 256
                                   + (chp ^ (row & 7)) * 8;
                __builtin_amdgcn_global_load_lds(
                    (const __attribute__((address_space(1))) void*)gb,
                    (__attribute__((address_space(3))) void*)&Bbuf[(c + 1) & 1][p * 8],
                    16, 0, 0);
            }
        }
        const u16* Bb = Bbuf[c & 1];
        const float en = enorm[c * 64 + rb];

        short8 bq[8];
        #pragma unroll
        for (int ks = 0; ks < 8; ++ks) {
            const int ch = ks * 4 + kseg;
            bq[ks] = *(const short8*)&Bb[(rb * 32 + (ch ^ (rb & 7))) * 8];
        }

        f32x4 acc[4];
        #pragma unroll
        for (int mf = 0; mf < 4; ++mf) acc[mf] = (f32x4){0.f, 0.f, 0.f, 0.f};
        #pragma unroll
        for (int ks = 0; ks < 8; ++ks)
            #pragma unroll
            for (int mf = 0; mf < 4; ++mf)
                acc[mf] = __builtin_amdgcn_mfma_f32_16x16x32_bf16(
                    afr[mf][ks], bq[ks], acc[mf], 0, 0, 0);

        const int col = c * 64 + rb;
        #pragma unroll
        for (int mf = 0; mf < 4; ++mf)
            #pragma unroll
            for (int r = 0; r < 4; ++r) {
                float d = fmaf(-2.f, acc[mf][r], en);
                if (d < best[mf][r]) { best[mf][r] = d; bidx[mf][r] = col; }
            }
        __syncthreads();   // Bb reads done; prefetched loads drained
    }

    // merge across the 16-lane col group (tie-break: smallest index)
    #pragma unroll
    for (int m = 1; m < 16; m <<= 1) {
        #pragma unroll
        for (int mf = 0; mf < 4; ++mf)
            #pragma unroll
            for (int r = 0; r < 4; ++r) {
                float b2 = __shfl_xor(best[mf][r], m);
                int   i2 = __shfl_xor(bidx[mf][r], m);
                if (b2 < best[mf][r] || (b2 == best[mf][r] && i2 < bidx[mf][r])) {
                    best[mf][r] = b2; bidx[mf][r] = i2;
                }
            }
    }
    if (lcol == 0) {
        #pragma unroll
        for (int mf = 0; mf < 4; ++mf)
            #pragma unroll
            for (int r = 0; r < 4; ++r) {
                const int rr = wrow * 64 + mf * 16 + kseg * 4 + r;
                ep_b[rr][wc] = best[mf][r];
                ep_i[rr][wc] = bidx[mf][r];
            }
    }
    __syncthreads();

    // final per-row merge; dist = ||x||^2 + best(enorm - 2 dot)
    if (tid < 128) {
        float b = ep_b[tid][0]; int bi = ep_i[tid][0];
        #pragma unroll
        for (int q = 1; q < 4; ++q) {
            float b2 = ep_b[tid][q]; int i2 = ep_i[tid][q];
            if (b2 < b || (b2 == b && i2 < bi)) { b = b2; bi = i2; }
        }
        inds[row0 + tid] = bi;
        atomicAdd(&hist[bi], 1);
        sred[tid] = (double)xn_lds[tid] + (double)b;
    }
    __syncthreads();
    for (int st = 64; st >= 1; st >>= 1) {
        if (tid < st) sred[tid] += sred[tid + st];
        __syncthreads();
    }
    if (tid == 0) partials[blockIdx.x] = sred[0];
}

// ---------------- write quantized output ----------------
__global__ __launch_bounds__(256) void writeq_kernel(const float* __restrict__ emb,
                                                     const int* __restrict__ inds,
                                                     float* __restrict__ out) {
    const int nvec = N_ROWS * DIM / 4;
    for (int idx = blockIdx.x * 256 + threadIdx.x; idx < nvec;
         idx += gridDim.x * 256) {
        int row = idx >> 6;
        int dv  = idx & 63;
        int k   = inds[row];
        ((float4*)out)[idx] = ((const float4*)(emb + (size_t)k * DIM))[dv];
    }
}

// ---------------- finalize: vq_loss + perplexity ----------------
__global__ __launch_bounds__(256) void finalize_kernel(const int* __restrict__ hist,
                                                       const double* __restrict__ partials,
                                                       int np,
                                                       float* __restrict__ out_tail) {
    __shared__ double sh[256];
    const int tid = threadIdx.x;
    double s = 0.0;
    for (int i = tid; i < np; i += 256) s += partials[i];
    sh[tid] = s; __syncthreads();
    for (int st = 128; st > 0; st >>= 1) {
        if (tid < st) sh[tid] += sh[tid + st];
        __syncthreads();
    }
    double sumsq = sh[0];
    __syncthreads();
    double e = 0.0;
    for (int k = tid; k < KC; k += 256) {
        double p = (double)hist[k] / (double)N_ROWS;
        e += p * log(p + 1e-10);
    }
    sh[tid] = e; __syncthreads();
    for (int st = 128; st > 0; st >>= 1) {
        if (tid < st) sh[tid] += sh[tid + st];
        __syncthreads();
    }
    if (tid == 0) {
        double mse = sumsq / (double)((size_t)N_ROWS * DIM);
        out_tail[0] = (float)(1.25 * mse);
        out_tail[1] = (float)exp(-sh[0]);
    }
}

// ================= fallback path (ws too small) =================
__global__ __launch_bounds__(256) void enorm_kernel(const float* __restrict__ emb,
                                                    float* __restrict__ enorm) {
    int k = blockIdx.x * blockDim.x + threadIdx.x;
    if (k >= KC) return;
    const float4* row = (const float4*)(emb + (size_t)k * DIM);
    float s = 0.f;
    #pragma unroll 4
    for (int i = 0; i < DIM / 4; ++i) {
        float4 v = row[i];
        s += v.x * v.x + v.y * v.y + v.z * v.z + v.w * v.w;
    }
    enorm[k] = s;
}

__global__ __launch_bounds__(256) void argmin_kernel(const float* __restrict__ lat,
                                                     const float* __restrict__ emb,
                                                     const float* __restrict__ enorm,
                                                     int* __restrict__ inds,
                                                     int* __restrict__ hist) {
    __shared__ float As[DSTEP][PAD_M];
    __shared__ float Bs[DSTEP][PAD_M];
    __shared__ float rbest[BM][17];
    __shared__ int   ridx[BM][17];

    const int tid = threadIdx.x;
    const int tx = tid & 15;
    const int ty = tid >> 4;
    const int row0 = blockIdx.x * BM;
    const int lm  = tid >> 2;
    const int ld0 = (tid & 3) * 8;

    float best[4];
    int bidx[4];
    #pragma unroll
    for (int i = 0; i < 4; ++i) { best[i] = INFINITY; bidx[i] = 0; }

    for (int ct = 0; ct < KC / BN; ++ct) {
        float acc[4][4];
        #pragma unroll
        for (int i = 0; i < 4; ++i)
            #pragma unroll
            for (int j = 0; j < 4; ++j) acc[i][j] = 0.f;

        for (int dc = 0; dc < DIM; dc += DSTEP) {
            const float* ap = lat + (size_t)(row0 + lm) * DIM + dc + ld0;
            float4 a0 = *(const float4*)ap;
            float4 a1 = *(const float4*)(ap + 4);
            As[ld0 + 0][lm] = a0.x; As[ld0 + 1][lm] = a0.y;
            As[ld0 + 2][lm] = a0.z; As[ld0 + 3][lm] = a0.w;
            As[ld0 + 4][lm] = a1.x; As[ld0 + 5][lm] = a1.y;
            As[ld0 + 6][lm] = a1.z; As[ld0 + 7][lm] = a1.w;
            const float* bp = emb + (size_t)(ct * BN + lm) * DIM + dc + ld0;
            float4 b0 = *(const float4*)bp;
            float4 b1 = *(const float4*)(bp + 4);
            Bs[ld0 + 0][lm] = b0.x; Bs[ld0 + 1][lm] = b0.y;
            Bs[ld0 + 2][lm] = b0.z; Bs[ld0 + 3][lm] = b0.w;
            Bs[ld0 + 4][lm] = b1.x; Bs[ld0 + 5][lm] = b1.y;
            Bs[ld0 + 6][lm] = b1.z; Bs[ld0 + 7][lm] = b1.w;
            __syncthreads();
            #pragma unroll
            for (int d = 0; d < DSTEP; ++d) {
                float4 av = *(const float4*)&As[d][ty * 4];
                float4 bv = *(const float4*)&Bs[d][tx * 4];
                float a[4] = {av.x, av.y, av.z, av.w};
                float b[4] = {bv.x, bv.y, bv.z, bv.w};
                #pragma unroll
                for (int i = 0; i < 4; ++i)
                    #pragma unroll
                    for (int j = 0; j < 4; ++j)
                        acc[i][j] = fmaf(a[i], b[j], acc[i][j]);
            }
            __syncthreads();
        }
        #pragma unroll
        for (int j = 0; j < 4; ++j) {
            int n = ct * BN + tx * 4 + j;
            float en = enorm[n];
            #pragma unroll
            for (int i = 0; i < 4; ++i) {
                float dist = fmaf(-2.f, acc[i][j], en);
                if (dist < best[i]) { best[i] = dist; bidx[i] = n; }
            }
        }
    }
    #pragma unroll
    for (int i = 0; i < 4; ++i) {
        rbest[ty * 4 + i][tx] = best[i];
        ridx [ty * 4 + i][tx] = bidx[i];
    }
    __syncthreads();
    if (tid < BM) {
        float g1 = INFINITY;
        int i1 = 0x7fffffff;
        for (int t = 0; t < 16; ++t) {
            float d = rbest[tid][t];
            int   ix = ridx[tid][t];
            if (d < g1 || (d == g1 && ix < i1)) { g1 = d; i1 = ix; }
        }
        inds[row0 + tid] = i1;
        atomicAdd(&hist[i1], 1);
    }
}

__global__ __launch_bounds__(256) void gather_kernel(const float* __restrict__ lat,
                                                     const float* __restrict__ emb,
                                                     const int* __restrict__ inds,
                                                     float* __restrict__ out,
                                                     double* __restrict__ partials) {
    __shared__ double wsum[4];
    const int tid = threadIdx.x;
    double acc = 0.0;
    const int nvec = N_ROWS * DIM / 4;
    for (int idx = blockIdx.x * blockDim.x + tid; idx < nvec; idx += gridDim.x * blockDim.x) {
        int row = idx >> 6;
        int dv = idx & 63;
        int k = inds[row];
        float4 xv = ((const float4*)lat)[idx];
        float4 qv = ((const float4*)(emb + (size_t)k * DIM))[dv];
        float d0 = qv.x - xv.x, d1 = qv.y - xv.y, d2 = qv.z - xv.z, d3 = qv.w - xv.w;
        float4 o;
        o.x = xv.x + d0; o.y = xv.y + d1; o.z = xv.z + d2; o.w = xv.w + d3;
        ((float4*)out)[idx] = o;
        acc += (double)d0 * d0 + (double)d1 * d1 + (double)d2 * d2 + (double)d3 * d3;
    }
    #pragma unroll
    for (int off = 32; off >= 1; off >>= 1) acc += __shfl_xor(acc, off);
    if ((tid & 63) == 0) wsum[tid >> 6] = acc;
    __syncthreads();
    if (tid == 0) partials[blockIdx.x] = wsum[0] + wsum[1] + wsum[2] + wsum[3];
}

extern "C" void kernel_launch(void* const* d_in, const int* in_sizes, int n_in,
                              void* d_out, int out_size, void* d_ws, size_t ws_size,
                              hipStream_t stream) {
    const float* lat = (const float*)d_in[0];
    const float* emb = (const float*)d_in[1];
    float* out = (float*)d_out;

    char* ws = (char*)d_ws;
    int*    hist     = (int*)(ws);                    // 4 KB
    float*  enorm    = (float*)(ws + 4096);           // 4 KB
    int*    inds     = (int*)(ws + 8192);             // 128 KB
    double* partials = (double*)(ws + 139264);        // 16 KB
    u16*    eh       = (u16*)(ws + 155648);           // 512 KB
    const size_t WS_NEED = 155648 + 524288;

    hipMemsetAsync(hist, 0, KC * sizeof(int), stream);

    if (ws_size >= WS_NEED) {
        split_e_kernel<<<KC / 4, 256, 0, stream>>>(emb, eh, enorm);
        fused_argmin_kernel<<<N_ROWS / 128, 512, 0, stream>>>(lat, eh, enorm,
                                                              inds, hist, partials);
        writeq_kernel<<<2048, 256, 0, stream>>>(emb, inds, out);
        finalize_kernel<<<1, 256, 0, stream>>>(hist, partials, N_ROWS / 128,
                                               out + (size_t)N_ROWS * DIM);
    } else {
        enorm_kernel<<<KC / 256, 256, 0, stream>>>(emb, enorm);
        argmin_kernel<<<N_ROWS / BM, 256, 0, stream>>>(lat, emb, enorm, inds, hist);
        gather_kernel<<<2048, 256, 0, stream>>>(lat, emb, inds, out, partials);
        finalize_kernel<<<1, 256, 0, stream>>>(hist, partials, 2048,
                                               out + (size_t)N_ROWS * DIM);
    }
}

// Round 10
// 58.504 us; speedup vs baseline: 30.9924x; 1.0487x over previous
//
#include <hip/hip_runtime.h>
#include <math.h>

#define N_ROWS 32768
#define DIM    256
#define KC     1024
#define BM     64
#define BN     64
#define DSTEP  32
#define PAD_M  68

typedef unsigned short u16;
typedef __attribute__((ext_vector_type(8))) short short8;
typedef __attribute__((ext_vector_type(4))) float f32x4;

__device__ __forceinline__ u16 bf16_rne(float f) {
    unsigned u = __float_as_uint(f);
    return (u16)((u + 0x7fffu + ((u >> 16) & 1u)) >> 16);
}

// ---------------- split codebook f32 -> bf16, fused row norms ----------------
__global__ __launch_bounds__(256) void split_e_kernel(const float* __restrict__ emb,
                                                      u16* __restrict__ hi,
                                                      float* __restrict__ enorm) {
    const int lane = threadIdx.x & 63;
    const int row  = blockIdx.x * 4 + (threadIdx.x >> 6);
    float4 v = ((const float4*)(emb + (size_t)row * DIM))[lane];
    ushort4 hv;
    hv.x = bf16_rne(v.x); hv.y = bf16_rne(v.y);
    hv.z = bf16_rne(v.z); hv.w = bf16_rne(v.w);
    ((ushort4*)(hi + (size_t)row * DIM))[lane] = hv;
    float ss = v.x * v.x + v.y * v.y + v.z * v.z + v.w * v.w;
    #pragma unroll
    for (int off = 32; off >= 1; off >>= 1) ss += __shfl_xor(ss, off);
    if (lane == 0) enorm[row] = ss;
}

// ---------------- fused argmin (4x2 wave grid: afr fits default reg budget) --------
// Block: 512 thr / 8 waves = 4 row-groups x 2 col-groups; 128 rows x 1024 cols.
// Wave tile 32 rows x 32 cols: afr[2][8] = 64 VGPR — small enough that the RA
// keeps it resident WITHOUT occupancy attributes (r8/r9 lesson: a 128-reg hoist
// gets remat'd from LDS regardless of budget; live set must fit ~128).
// A staged once into swizzled LDS (f32->bf16) then hoisted; B double-buffered
// 64-col chunks via global_load_lds (pre-swizzled source); one barrier per chunk.
// Main loop per wave per chunk: 16 ds_read_b128 (B only) + 32 MFMA.
__global__ __launch_bounds__(512) void fused_argmin_kernel(
        const float* __restrict__ lat, const u16* __restrict__ eh,
        const float* __restrict__ enorm,
        int* __restrict__ inds, int* __restrict__ hist,
        double* __restrict__ partials) {
    __shared__ u16    Atile[128 * 256];   // 64 KB, swizzled
    __shared__ u16    Bbuf[2][64 * 256];  // 2 x 32 KB, swizzled (via src)
    __shared__ float  xn_lds[128];
    __shared__ float  ep_b[128][2];
    __shared__ int    ep_i[128][2];
    __shared__ double sred[128];

    const int tid  = threadIdx.x;
    const int l    = tid & 63;
    const int w    = tid >> 6;
    const int wrow = w >> 1;        // 0..3 : row group (32 rows each)
    const int wc   = w & 1;         // 0..1 : col group (32 cols per 64-col chunk)
    const int lcol = l & 15;
    const int kseg = l >> 4;        // 0..3
    const size_t row0 = (size_t)blockIdx.x * 128;

    // ---- prologue: stage A (f32->bf16, swizzled) + per-row ||x||^2 ----
    #pragma unroll
    for (int i = 0; i < 8; ++i) {
        const int p   = i * 512 + tid;   // 0..4095 = 128 rows x 32 chunks
        const int row = p >> 5;
        const int chl = p & 31;
        const float* src = lat + (row0 + row) * 256 + chl * 8;
        float4 v0 = *(const float4*)src;
        float4 v1 = *(const float4*)(src + 4);
        short8 d;
        d[0] = (short)bf16_rne(v0.x); d[1] = (short)bf16_rne(v0.y);
        d[2] = (short)bf16_rne(v0.z); d[3] = (short)bf16_rne(v0.w);
        d[4] = (short)bf16_rne(v1.x); d[5] = (short)bf16_rne(v1.y);
        d[6] = (short)bf16_rne(v1.z); d[7] = (short)bf16_rne(v1.w);
        *(short8*)&Atile[(row * 32 + (chl ^ (row & 7))) * 8] = d;
        // row-norm: 32 consecutive threads (one 32-lane group) share a row
        float ss = v0.x * v0.x + v0.y * v0.y + v0.z * v0.z + v0.w * v0.w
                 + v1.x * v1.x + v1.y * v1.y + v1.z * v1.z + v1.w * v1.w;
        ss += __shfl_xor(ss, 1);  ss += __shfl_xor(ss, 2);
        ss += __shfl_xor(ss, 4);  ss += __shfl_xor(ss, 8);
        ss += __shfl_xor(ss, 16);
        if ((tid & 31) == 0) xn_lds[row] = ss;   // unique writer per row
    }
    // issue B chunk 0 (pre-swizzled global source, linear LDS dest)
    #pragma unroll
    for (int i = 0; i < 4; ++i) {
        const int p = i * 512 + tid;     // 0..2047 = 64 rows x 32 chunks
        const int row = p >> 5;
        const int chp = p & 31;
        const u16* gb = eh + (size_t)row * 256 + (chp ^ (row & 7)) * 8;
        __builtin_amdgcn_global_load_lds(
            (const __attribute__((address_space(1))) void*)gb,
            (__attribute__((address_space(3))) void*)&Bbuf[0][p * 8], 16, 0, 0);
    }
    __syncthreads();

    // ---- hoist A fragments into registers (64 VGPR — read LDS once) ----
    short8 afr[2][8];
    #pragma unroll
    for (int mf = 0; mf < 2; ++mf) {
        const int ra = wrow * 32 + mf * 16 + lcol;
        #pragma unroll
        for (int ks = 0; ks < 8; ++ks) {
            const int ch = ks * 4 + kseg;
            afr[mf][ks] = *(const short8*)&Atile[(ra * 32 + (ch ^ (ra & 7))) * 8];
        }
    }
    __builtin_amdgcn_sched_barrier(0);   // keep the hoist hoisted

    float best[2][4];
    int   bidx[2][4];
    #pragma unroll
    for (int mf = 0; mf < 2; ++mf)
        #pragma unroll
        for (int r = 0; r < 4; ++r) { best[mf][r] = INFINITY; bidx[mf][r] = 0; }

    const int rb0 = wc * 32 + lcol;      // nf = 0 column row-in-B
    const int rb1 = rb0 + 16;            // nf = 1
    for (int c = 0; c < 16; ++c) {
        if (c < 15) {   // prefetch next chunk into the other buffer
            #pragma unroll
            for (int i = 0; i < 4; ++i) {
                const int p = i * 512 + tid;
                const int row = p >> 5;
                const int chp = p & 31;
                const u16* gb = eh + (size_t)((c + 1) * 64 + row) * 256
                                   + (chp ^ (row & 7)) * 8;
                __builtin_amdgcn_global_load_lds(
                    (const __attribute__((address_space(1))) void*)gb,
                    (__attribute__((address_space(3))) void*)&Bbuf[(c + 1) & 1][p * 8],
                    16, 0, 0);
            }
        }
        const u16* Bb = Bbuf[c & 1];
        const float en0 = enorm[c * 64 + rb0];
        const float en1 = enorm[c * 64 + rb1];

        f32x4 acc[2][2];
        #pragma unroll
        for (int mf = 0; mf < 2; ++mf)
            #pragma unroll
            for (int nf = 0; nf < 2; ++nf)
                acc[mf][nf] = (f32x4){0.f, 0.f, 0.f, 0.f};

        #pragma unroll
        for (int ks = 0; ks < 8; ++ks) {
            const int ch = ks * 4 + kseg;
            short8 b0 = *(const short8*)&Bb[(rb0 * 32 + (ch ^ (rb0 & 7))) * 8];
            short8 b1 = *(const short8*)&Bb[(rb1 * 32 + (ch ^ (rb1 & 7))) * 8];
            #pragma unroll
            for (int mf = 0; mf < 2; ++mf) {
                acc[mf][0] = __builtin_amdgcn_mfma_f32_16x16x32_bf16(
                    afr[mf][ks], b0, acc[mf][0], 0, 0, 0);
                acc[mf][1] = __builtin_amdgcn_mfma_f32_16x16x32_bf16(
                    afr[mf][ks], b1, acc[mf][1], 0, 0, 0);
            }
        }

        const int col0 = c * 64 + rb0;
        const int col1 = c * 64 + rb1;
        #pragma unroll
        for (int mf = 0; mf < 2; ++mf)
            #pragma unroll
            for (int r = 0; r < 4; ++r) {
                float d0 = fmaf(-2.f, acc[mf][0][r], en0);
                if (d0 < best[mf][r]) { best[mf][r] = d0; bidx[mf][r] = col0; }
                float d1 = fmaf(-2.f, acc[mf][1][r], en1);
                if (d1 < best[mf][r]) { best[mf][r] = d1; bidx[mf][r] = col1; }
            }
        __syncthreads();   // Bb reads done; prefetched loads drained
    }

    // merge across the 16-lane col group (tie-break: smallest index)
    #pragma unroll
    for (int m = 1; m < 16; m <<= 1) {
        #pragma unroll
        for (int mf = 0; mf < 2; ++mf)
            #pragma unroll
            for (int r = 0; r < 4; ++r) {
                float b2 = __shfl_xor(best[mf][r], m);
                int   i2 = __shfl_xor(bidx[mf][r], m);
                if (b2 < best[mf][r] || (b2 == best[mf][r] && i2 < bidx[mf][r])) {
                    best[mf][r] = b2; bidx[mf][r] = i2;
                }
            }
    }
    if (lcol == 0) {
        #pragma unroll
        for (int mf = 0; mf < 2; ++mf)
            #pragma unroll
            for (int r = 0; r < 4; ++r) {
                const int rr = wrow * 32 + mf * 16 + kseg * 4 + r;
                ep_b[rr][wc] = best[mf][r];
                ep_i[rr][wc] = bidx[mf][r];
            }
    }
    __syncthreads();

    // final per-row merge; dist = ||x||^2 + best(enorm - 2 dot)
    if (tid < 128) {
        float b = ep_b[tid][0]; int bi = ep_i[tid][0];
        float b2 = ep_b[tid][1]; int i2 = ep_i[tid][1];
        if (b2 < b || (b2 == b && i2 < bi)) { b = b2; bi = i2; }
        inds[row0 + tid] = bi;
        atomicAdd(&hist[bi], 1);
        sred[tid] = (double)xn_lds[tid] + (double)b;
    }
    __syncthreads();
    for (int st = 64; st >= 1; st >>= 1) {
        if (tid < st) sred[tid] += sred[tid + st];
        __syncthreads();
    }
    if (tid == 0) partials[blockIdx.x] = sred[0];
}

// ---------------- write quantized output ----------------
__global__ __launch_bounds__(256) void writeq_kernel(const float* __restrict__ emb,
                                                     const int* __restrict__ inds,
                                                     float* __restrict__ out) {
    const int nvec = N_ROWS * DIM / 4;
    for (int idx = blockIdx.x * 256 + threadIdx.x; idx < nvec;
         idx += gridDim.x * 256) {
        int row = idx >> 6;
        int dv  = idx & 63;
        int k   = inds[row];
        ((float4*)out)[idx] = ((const float4*)(emb + (size_t)k * DIM))[dv];
    }
}

// ---------------- finalize: vq_loss + perplexity ----------------
__global__ __launch_bounds__(256) void finalize_kernel(const int* __restrict__ hist,
                                                       const double* __restrict__ partials,
                                                       int np,
                                                       float* __restrict__ out_tail) {
    __shared__ double sh[256];
    const int tid = threadIdx.x;
    double s = 0.0;
    for (int i = tid; i < np; i += 256) s += partials[i];
    sh[tid] = s; __syncthreads();
    for (int st = 128; st > 0; st >>= 1) {
        if (tid < st) sh[tid] += sh[tid + st];
        __syncthreads();
    }
    double sumsq = sh[0];
    __syncthreads();
    double e = 0.0;
    for (int k = tid; k < KC; k += 256) {
        double p = (double)hist[k] / (double)N_ROWS;
        e += p * log(p + 1e-10);
    }
    sh[tid] = e; __syncthreads();
    for (int st = 128; st > 0; st >>= 1) {
        if (tid < st) sh[tid] += sh[tid + st];
        __syncthreads();
    }
    if (tid == 0) {
        double mse = sumsq / (double)((size_t)N_ROWS * DIM);
        out_tail[0] = (float)(1.25 * mse);
        out_tail[1] = (float)exp(-sh[0]);
    }
}

// ================= fallback path (ws too small) =================
__global__ __launch_bounds__(256) void enorm_kernel(const float* __restrict__ emb,
                                                    float* __restrict__ enorm) {
    int k = blockIdx.x * blockDim.x + threadIdx.x;
    if (k >= KC) return;
    const float4* row = (const float4*)(emb + (size_t)k * DIM);
    float s = 0.f;
    #pragma unroll 4
    for (int i = 0; i < DIM / 4; ++i) {
        float4 v = row[i];
        s += v.x * v.x + v.y * v.y + v.z * v.z + v.w * v.w;
    }
    enorm[k] = s;
}

__global__ __launch_bounds__(256) void argmin_kernel(const float* __restrict__ lat,
                                                     const float* __restrict__ emb,
                                                     const float* __restrict__ enorm,
                                                     int* __restrict__ inds,
                                                     int* __restrict__ hist) {
    __shared__ float As[DSTEP][PAD_M];
    __shared__ float Bs[DSTEP][PAD_M];
    __shared__ float rbest[BM][17];
    __shared__ int   ridx[BM][17];

    const int tid = threadIdx.x;
    const int tx = tid & 15;
    const int ty = tid >> 4;
    const int row0 = blockIdx.x * BM;
    const int lm  = tid >> 2;
    const int ld0 = (tid & 3) * 8;

    float best[4];
    int bidx[4];
    #pragma unroll
    for (int i = 0; i < 4; ++i) { best[i] = INFINITY; bidx[i] = 0; }

    for (int ct = 0; ct < KC / BN; ++ct) {
        float acc[4][4];
        #pragma unroll
        for (int i = 0; i < 4; ++i)
            #pragma unroll
            for (int j = 0; j < 4; ++j) acc[i][j] = 0.f;

        for (int dc = 0; dc < DIM; dc += DSTEP) {
            const float* ap = lat + (size_t)(row0 + lm) * DIM + dc + ld0;
            float4 a0 = *(const float4*)ap;
            float4 a1 = *(const float4*)(ap + 4);
            As[ld0 + 0][lm] = a0.x; As[ld0 + 1][lm] = a0.y;
            As[ld0 + 2][lm] = a0.z; As[ld0 + 3][lm] = a0.w;
            As[ld0 + 4][lm] = a1.x; As[ld0 + 5][lm] = a1.y;
            As[ld0 + 6][lm] = a1.z; As[ld0 + 7][lm] = a1.w;
            const float* bp = emb + (size_t)(ct * BN + lm) * DIM + dc + ld0;
            float4 b0 = *(const float4*)bp;
            float4 b1 = *(const float4*)(bp + 4);
            Bs[ld0 + 0][lm] = b0.x; Bs[ld0 + 1][lm] = b0.y;
            Bs[ld0 + 2][lm] = b0.z; Bs[ld0 + 3][lm] = b0.w;
            Bs[ld0 + 4][lm] = b1.x; Bs[ld0 + 5][lm] = b1.y;
            Bs[ld0 + 6][lm] = b1.z; Bs[ld0 + 7][lm] = b1.w;
            __syncthreads();
            #pragma unroll
            for (int d = 0; d < DSTEP; ++d) {
                float4 av = *(const float4*)&As[d][ty * 4];
                float4 bv = *(const float4*)&Bs[d][tx * 4];
                float a[4] = {av.x, av.y, av.z, av.w};
                float b[4] = {bv.x, bv.y, bv.z, bv.w};
                #pragma unroll
                for (int i = 0; i < 4; ++i)
                    #pragma unroll
                    for (int j = 0; j < 4; ++j)
                        acc[i][j] = fmaf(a[i], b[j], acc[i][j]);
            }
            __syncthreads();
        }
        #pragma unroll
        for (int j = 0; j < 4; ++j) {
            int n = ct * BN + tx * 4 + j;
            float en = enorm[n];
            #pragma unroll
            for (int i = 0; i < 4; ++i) {
                float dist = fmaf(-2.f, acc[i][j], en);
                if (dist < best[i]) { best[i] = dist; bidx[i] = n; }
            }
        }
    }
    #pragma unroll
    for (int i = 0; i < 4; ++i) {
        rbest[ty * 4 + i][tx] = best[i];
        ridx [ty * 4 + i][tx] = bidx[i];
    }
    __syncthreads();
    if (tid < BM) {
        float g1 = INFINITY;
        int i1 = 0x7fffffff;
        for (int t = 0; t < 16; ++t) {
            float d = rbest[tid][t];
            int   ix = ridx[tid][t];
            if (d < g1 || (d == g1 && ix < i1)) { g1 = d; i1 = ix; }
        }
        inds[row0 + tid] = i1;
        atomicAdd(&hist[i1], 1);
    }
}

__global__ __launch_bounds__(256) void gather_kernel(const float* __restrict__ lat,
                                                     const float* __restrict__ emb,
                                                     const int* __restrict__ inds,
                                                     float* __restrict__ out,
                                                     double* __restrict__ partials) {
    __shared__ double wsum[4];
    const int tid = threadIdx.x;
    double acc = 0.0;
    const int nvec = N_ROWS * DIM / 4;
    for (int idx = blockIdx.x * blockDim.x + tid; idx < nvec; idx += gridDim.x * blockDim.x) {
        int row = idx >> 6;
        int dv = idx & 63;
        int k = inds[row];
        float4 xv = ((const float4*)lat)[idx];
        float4 qv = ((const float4*)(emb + (size_t)k * DIM))[dv];
        float d0 = qv.x - xv.x, d1 = qv.y - xv.y, d2 = qv.z - xv.z, d3 = qv.w - xv.w;
        float4 o;
        o.x = xv.x + d0; o.y = xv.y + d1; o.z = xv.z + d2; o.w = xv.w + d3;
        ((float4*)out)[idx] = o;
        acc += (double)d0 * d0 + (double)d1 * d1 + (double)d2 * d2 + (double)d3 * d3;
    }
    #pragma unroll
    for (int off = 32; off >= 1; off >>= 1) acc += __shfl_xor(acc, off);
    if ((tid & 63) == 0) wsum[tid >> 6] = acc;
    __syncthreads();
    if (tid == 0) partials[blockIdx.x] = wsum[0] + wsum[1] + wsum[2] + wsum[3];
}

extern "C" void kernel_launch(void* const* d_in, const int* in_sizes, int n_in,
                              void* d_out, int out_size, void* d_ws, size_t ws_size,
                              hipStream_t stream) {
    const float* lat = (const float*)d_in[0];
    const float* emb = (const float*)d_in[1];
    float* out = (float*)d_out;

    char* ws = (char*)d_ws;
    int*    hist     = (int*)(ws);                    // 4 KB
    float*  enorm    = (float*)(ws + 4096);           // 4 KB
    int*    inds     = (int*)(ws + 8192);             // 128 KB
    double* partials = (double*)(ws + 139264);        // 16 KB
    u16*    eh       = (u16*)(ws + 155648);           // 512 KB
    const size_t WS_NEED = 155648 + 524288;

    hipMemsetAsync(hist, 0, KC * sizeof(int), stream);

    if (ws_size >= WS_NEED) {
        split_e_kernel<<<KC / 4, 256, 0, stream>>>(emb, eh, enorm);
        fused_argmin_kernel<<<N_ROWS / 128, 512, 0, stream>>>(lat, eh, enorm,
                                                              inds, hist, partials);
        writeq_kernel<<<2048, 256, 0, stream>>>(emb, inds, out);
        finalize_kernel<<<1, 256, 0, stream>>>(hist, partials, N_ROWS / 128,
                                               out + (size_t)N_ROWS * DIM);
    } else {
        enorm_kernel<<<KC / 256, 256, 0, stream>>>(emb, enorm);
        argmin_kernel<<<N_ROWS / BM, 256, 0, stream>>>(lat, emb, enorm, inds, hist);
        gather_kernel<<<2048, 256, 0, stream>>>(lat, emb, inds, out, partials);
        finalize_kernel<<<1, 256, 0, stream>>>(hist, partials, 2048,
                                               out + (size_t)N_ROWS * DIM);
    }
}